// Round 10
// baseline (685.885 us; speedup 1.0000x reference)
//
#include <hip/hip_runtime.h>
#include <hip/hip_bf16.h>
#include <math.h>

// Problem constants
#define D_MODEL 1024
#define D_FF    4096
#define N_EXP   8
#define TOKENS  2048          // 2 * 1024
#define THRESH  0.8f
#define EPS_R   1e-6f

#define FINAL_SIZE (TOKENS * D_MODEL)   // 2097152

typedef unsigned short ushort_t;
typedef __attribute__((ext_vector_type(4))) float f32x4;
typedef __attribute__((ext_vector_type(8))) short bf16x8;
typedef __attribute__((ext_vector_type(8))) unsigned short ushort8_t;

__device__ __forceinline__ unsigned short f2bf(float f) {
    unsigned u = __builtin_bit_cast(unsigned, f);
    unsigned r = (u + 0x7FFFu + ((u >> 16) & 1u)) >> 16;
    return (unsigned short)r;
}

// async global->LDS, 16B per lane; lds base must be wave-uniform (+lane*16 implicit)
template <typename T>
__device__ __forceinline__ void gload16(const T* gsrc, T* ldst) {
    __builtin_amdgcn_global_load_lds((const __attribute__((address_space(1))) unsigned int*)gsrc,
                                     (__attribute__((address_space(3))) unsigned int*)ldst,
                                     16, 0, 0);
}

// counted-vmcnt pipeline primitives: keep next-tile loads in flight across barriers
#define VMCNT4() asm volatile("s_waitcnt vmcnt(4)" ::: "memory")
#define VMCNT0() asm volatile("s_waitcnt vmcnt(0)" ::: "memory")
#define BAR()    do { __builtin_amdgcn_s_barrier(); asm volatile("" ::: "memory"); } while (0)

// Conflict-free LDS tile layout: [row>>3][chunk 0..3][row&7][16B].
// Fragment read (16 consecutive rows, chunk=lane>>4) hits bank (lane&7)*4 -> no conflicts.
// ushort offset of (row, chunk):
__device__ __forceinline__ int swz(int row, int c) {
    return ((row >> 3) << 8) + (c << 6) + ((row & 7) << 3);
}

// ---------------------------------------------------------------- convert x fp32 -> bf16
__global__ __launch_bounds__(256) void convert_x_kernel(const float* __restrict__ x,
                                                        ushort_t* __restrict__ xbf) {
    int i = blockIdx.x * 256 + threadIdx.x;
    const float4 v = reinterpret_cast<const float4*>(x)[i];
    ushort4 o;
    o.x = f2bf(v.x); o.y = f2bf(v.y); o.z = f2bf(v.z); o.w = f2bf(v.w);
    reinterpret_cast<ushort4*>(xbf)[i] = o;
}

// ---------------------------------------------------------------- weight transpose+convert
// in: [K][N] fp32 (expert z at z*K*N), out: [N][K] bf16. Tile 32(k) x 64(n), 256 thr.
__global__ __launch_bounds__(256) void wconv_kernel(const float* __restrict__ in,
                                                    ushort_t* __restrict__ out,
                                                    int K, int N) {
    __shared__ float sT[32][65];
    const int e = blockIdx.z;
    const float* src = in + (size_t)e * K * N;
    ushort_t* dst = out + (size_t)e * K * N;
    const int k0 = blockIdx.y * 32, n0 = blockIdx.x * 64;
    const int t = threadIdx.x;
    {
        const int k = t >> 3;              // 0..31
        const int n4 = (t & 7) * 8;        // 0..56
        const float* s = src + (size_t)(k0 + k) * N + n0 + n4;
        float4 a = *reinterpret_cast<const float4*>(s);
        float4 b = *reinterpret_cast<const float4*>(s + 4);
        sT[k][n4 + 0] = a.x; sT[k][n4 + 1] = a.y; sT[k][n4 + 2] = a.z; sT[k][n4 + 3] = a.w;
        sT[k][n4 + 4] = b.x; sT[k][n4 + 5] = b.y; sT[k][n4 + 6] = b.z; sT[k][n4 + 7] = b.w;
    }
    __syncthreads();
    {
        const int n = t >> 2;              // 0..63
        const int kg = (t & 3) * 8;        // 0..24
        ushort8_t o;
#pragma unroll
        for (int j = 0; j < 8; ++j) o[j] = f2bf(sT[kg + j][n]);
        *reinterpret_cast<ushort8_t*>(dst + (size_t)(n0 + n) * K + k0 + kg) = o;
    }
}

// ---------------------------------------------------------------- router (one wave per token)
__global__ __launch_bounds__(256) void router_kernel(const float* __restrict__ x,
                                                     const float* __restrict__ Wg,
                                                     const float* __restrict__ bg,
                                                     float* __restrict__ wts,     // [T][8]
                                                     float* __restrict__ probs,   // [T][8]
                                                     float* __restrict__ ent,     // [T]
                                                     float* __restrict__ act_out) // [T]
{
    int wave = threadIdx.x >> 6;
    int lane = threadIdx.x & 63;
    int t = blockIdx.x * 4 + wave;

    float acc[8];
#pragma unroll
    for (int e = 0; e < 8; ++e) acc[e] = 0.f;

    const float* xrow = x + (size_t)t * D_MODEL;
    for (int d = lane; d < D_MODEL; d += 64) {
        float xv = xrow[d];
        const float4* wg = reinterpret_cast<const float4*>(Wg + (size_t)d * 8);
        float4 a = wg[0], b = wg[1];
        acc[0] += xv * a.x; acc[1] += xv * a.y; acc[2] += xv * a.z; acc[3] += xv * a.w;
        acc[4] += xv * b.x; acc[5] += xv * b.y; acc[6] += xv * b.z; acc[7] += xv * b.w;
    }
#pragma unroll
    for (int e = 0; e < 8; ++e) {
#pragma unroll
        for (int off = 32; off > 0; off >>= 1) acc[e] += __shfl_xor(acc[e], off);
    }

    if (lane == 0) {
        float l[8], p[8];
        float m = -1e30f;
#pragma unroll
        for (int e = 0; e < 8; ++e) { l[e] = acc[e] + bg[e]; m = fmaxf(m, l[e]); }
        float s = 0.f;
#pragma unroll
        for (int e = 0; e < 8; ++e) { p[e] = expf(l[e] - m); s += p[e]; }
        float inv = 1.f / s;
#pragma unroll
        for (int e = 0; e < 8; ++e) p[e] *= inv;

        int idx[8]; float sp[8];
#pragma unroll
        for (int e = 0; e < 8; ++e) { idx[e] = e; sp[e] = p[e]; }
        for (int i = 0; i < 8; ++i) {
            int best = i;
            for (int j = i + 1; j < 8; ++j) if (sp[j] > sp[best]) best = j;
            float tv = sp[i]; sp[i] = sp[best]; sp[best] = tv;
            int ti = idx[i]; idx[i] = idx[best]; idx[best] = ti;
        }
        float cum = 0.f, asum = 0.f, ap[8];
        int cnt = 0;
        for (int i = 0; i < 8; ++i) {
            int active = (i == 0) || (cum < THRESH);
            cum += sp[i];
            ap[i] = active ? sp[i] : 0.f;
            asum += ap[i];
            cnt += active;
        }
        float rinv = 1.f / (asum + EPS_R);
        float w[8];
        for (int i = 0; i < 8; ++i) w[idx[i]] = ap[i] * rinv;

        float* wrow = wts + (size_t)t * 8;
        float* prow = probs + (size_t)t * 8;
        float e_sum = 0.f;
#pragma unroll
        for (int e = 0; e < 8; ++e) {
            wrow[e] = w[e];
            prow[e] = p[e];
            e_sum -= p[e] * logf(p[e] + EPS_R);
        }
        ent[t] = e_sum;
        act_out[t] = (float)cnt;
    }
}

// ---------------------------------------------------------------- per-expert token compaction
__global__ __launch_bounds__(512) void build_lists_kernel(const float* __restrict__ wts,
                                                          int* __restrict__ tok,   // [8][T]
                                                          int* __restrict__ pos,   // [T][8]
                                                          int* __restrict__ cnt) { // [8]
    const int e = threadIdx.x >> 6;
    const int lane = threadIdx.x & 63;
    int base = 0;
    for (int t0 = 0; t0 < TOKENS; t0 += 64) {
        int t = t0 + lane;
        float w = wts[(size_t)t * 8 + e];
        unsigned long long mask = __ballot(w > 0.f);
        int rank = __popcll(mask & ((1ull << lane) - 1ull));
        if (w > 0.f) {
            tok[e * TOKENS + base + rank] = t;
            pos[(size_t)t * 8 + e] = base + rank;
        } else {
            pos[(size_t)t * 8 + e] = -1;
        }
        base += __popcll(mask);
    }
    if (lane == 0) cnt[e] = base;
}

// ---------------------------------------------------------------- loss reduce (single block, deterministic)
__global__ __launch_bounds__(256) void loss_kernel(const float* __restrict__ wts,
                                                   const float* __restrict__ probs,
                                                   const float* __restrict__ ent,
                                                   float* __restrict__ out_scalars) // [2]
{
    int tid = threadIdx.x;
    float fsum[8], psum[8], es = 0.f;
#pragma unroll
    for (int e = 0; e < 8; ++e) { fsum[e] = 0.f; psum[e] = 0.f; }
    for (int t = tid; t < TOKENS; t += 256) {
        const float* wrow = wts + (size_t)t * 8;
        const float* prow = probs + (size_t)t * 8;
#pragma unroll
        for (int e = 0; e < 8; ++e) {
            fsum[e] += (wrow[e] > 0.f) ? 1.f : 0.f;
            psum[e] += prow[e];
        }
        es += ent[t];
    }
    __shared__ float red[256];
    __shared__ float tot[17];
    for (int q = 0; q < 17; ++q) {
        float v = (q < 8) ? fsum[q] : ((q < 16) ? psum[q - 8] : es);
        red[tid] = v; __syncthreads();
        for (int s = 128; s > 0; s >>= 1) {
            if (tid < s) red[tid] += red[tid + s];
            __syncthreads();
        }
        if (tid == 0) tot[q] = red[0];
        __syncthreads();
    }
    if (tid == 0) {
        const float invT = 1.f / (float)TOKENS;
        float lb = 0.f;
        for (int e = 0; e < 8; ++e) lb += (tot[e] * invT) * (tot[8 + e] * invT);
        out_scalars[0] = 8.f * lb;
        out_scalars[1] = tot[16] * invT;
    }
}

// ---------------------------------------------------------------- GEMM1 (sparse M, counted-vmcnt dbuf, swizzled LDS)
// tile 128(M) x 64(N), BK=32, 4 waves (2x2), dual B (W1,W3); LDS 2x16 KB
__global__ __launch_bounds__(256, 2) void gemm1_kernel(const ushort_t* __restrict__ xbf, // [T][1024]
                                                       const ushort_t* __restrict__ w1t, // [GS][4096][1024]
                                                       const ushort_t* __restrict__ w3t,
                                                       const float* __restrict__ b1,     // [E][4096]
                                                       const float* __restrict__ b3,
                                                       const int* __restrict__ tok,      // [8][T]
                                                       const int* __restrict__ cnts,     // [8]
                                                       ushort_t* __restrict__ g,         // [GS][T][4096] compacted
                                                       int gbase) {
    const int z = blockIdx.z;
    const int ge = gbase + z;
    const int cnt = cnts[ge];

    // XCD swizzle: each XCD owns a contiguous chunk of 8 N-tiles
    const int NX = D_FF / 64;          // 64
    const int CHUNK = NX / 8;          // 8
    const int orig = blockIdx.x + NX * blockIdx.y;
    const int inner = orig >> 3;
    const int nx = (orig & 7) * CHUNK + (inner & (CHUNK - 1));
    const int ny = inner / CHUNK;      // 0..15
    const int m0 = ny * 128;
    const int n0 = nx * 64;
    if (m0 >= cnt) return;

    __shared__ ushort_t sA0[128 * 32], sA1[128 * 32];
    __shared__ ushort_t sB10[64 * 32], sB11[64 * 32];
    __shared__ ushort_t sB30[64 * 32], sB31[64 * 32];

    const int tid = threadIdx.x;
    const int lane = tid & 63;
    const int wave = tid >> 6;
    const int wr = wave >> 1, wc = wave & 1;

    f32x4 acc1[4][2], acc3[4][2];
#pragma unroll
    for (int i = 0; i < 4; ++i)
#pragma unroll
        for (int j = 0; j < 2; ++j) { acc1[i][j] = (f32x4)0.f; acc3[i][j] = (f32x4)0.f; }

    // source-permuted staging: instr covers 16 rows; lane -> (row, k-chunk)
    const int rIn = ((lane >> 5) << 3) + (lane & 7);   // 0..15
    const int cIn = (lane >> 3) & 3;                   // k-chunk 0..3

    // A: 8 instrs (2/wave): instr i = 2*wave+r covers rows 16i..16i+16
    const ushort_t* arow[2];
#pragma unroll
    for (int r = 0; r < 2; ++r) {
        int row = 32 * wave + 16 * r + rIn;            // 0..127
        int i = m0 + row;
        i = (i < cnt) ? i : (cnt - 1);
        arow[r] = xbf + (size_t)tok[ge * TOKENS + i] * D_MODEL + cIn * 8;
    }
    // B1/B3: 4 instrs each (1/wave): wave w covers rows 16w..16w+16
    const int brow = 16 * wave + rIn;                  // 0..63
    const ushort_t* w1row = w1t + (size_t)z * D_FF * D_MODEL + (size_t)(n0 + brow) * D_MODEL + cIn * 8;
    const ushort_t* w3row = w3t + (size_t)z * D_FF * D_MODEL + (size_t)(n0 + brow) * D_MODEL + cIn * 8;

    auto stage = [&](ushort_t* dA, ushort_t* dB1, ushort_t* dB3, int kk) {
        gload16(arow[0] + kk, dA + (wave * 2 + 0) * 512);
        gload16(arow[1] + kk, dA + (wave * 2 + 1) * 512);
        gload16(w1row + kk, dB1 + wave * 512);
        gload16(w3row + kk, dB3 + wave * 512);
    };
    const int c = lane >> 4;
    const int fr = lane & 15;
    auto compute = [&](const ushort_t* pA, const ushort_t* pB1, const ushort_t* pB3) {
        bf16x8 a[4], u1[2], u3[2];
#pragma unroll
        for (int fm = 0; fm < 4; ++fm)
            a[fm] = *reinterpret_cast<const bf16x8*>(&pA[swz(wr * 64 + fm * 16 + fr, c)]);
#pragma unroll
        for (int fn = 0; fn < 2; ++fn) {
            u1[fn] = *reinterpret_cast<const bf16x8*>(&pB1[swz(wc * 32 + fn * 16 + fr, c)]);
            u3[fn] = *reinterpret_cast<const bf16x8*>(&pB3[swz(wc * 32 + fn * 16 + fr, c)]);
        }
#pragma unroll
        for (int fm = 0; fm < 4; ++fm)
#pragma unroll
            for (int fn = 0; fn < 2; ++fn) {
                acc1[fm][fn] = __builtin_amdgcn_mfma_f32_16x16x32_bf16(a[fm], u1[fn], acc1[fm][fn], 0, 0, 0);
                acc3[fm][fn] = __builtin_amdgcn_mfma_f32_16x16x32_bf16(a[fm], u3[fn], acc3[fm][fn], 0, 0, 0);
            }
    };

    // counted-vmcnt pipeline: 32 K-steps, prefetch 1 tile deep (4 loads/stage)
    stage(sA0, sB10, sB30, 0);
#pragma unroll 1
    for (int t = 0; t < 30; t += 2) {
        stage(sA1, sB11, sB31, (t + 1) * 32);
        VMCNT4(); BAR();
        compute(sA0, sB10, sB30);
        BAR();
        stage(sA0, sB10, sB30, (t + 2) * 32);
        VMCNT4(); BAR();
        compute(sA1, sB11, sB31);
        BAR();
    }
    stage(sA1, sB11, sB31, 31 * 32);
    VMCNT4(); BAR();
    compute(sA0, sB10, sB30);
    BAR();
    VMCNT0(); BAR();
    compute(sA1, sB11, sB31);

    // epilogue: SwiGLU -> bf16 g (compacted rows, guarded)
    ushort_t* ge_out = g + (size_t)z * TOKENS * D_FF;
#pragma unroll
    for (int fn = 0; fn < 2; ++fn) {
        int col = n0 + wc * 32 + fn * 16 + fr;
        float bb1 = b1[(size_t)ge * D_FF + col];
        float bb3 = b3[(size_t)ge * D_FF + col];
#pragma unroll
        for (int fm = 0; fm < 4; ++fm) {
#pragma unroll
            for (int r = 0; r < 4; ++r) {
                int row = m0 + wr * 64 + fm * 16 + (lane >> 4) * 4 + r;
                if (row < cnt) {
                    float h1 = acc1[fm][fn][r] + bb1;
                    float h3 = acc3[fm][fn][r] + bb3;
                    float gv = (h1 / (1.f + expf(-h1))) * h3;
                    ge_out[(size_t)row * D_FF + col] = f2bf(gv);
                }
            }
        }
    }
}

// ---------------------------------------------------------------- GEMM2 (sparse M, counted-vmcnt dbuf, swizzled LDS)
// tile 128(M) x 128(N), BK=32, 4 waves (2x2, wave 64x64); LDS 32 KB dbuf
__global__ __launch_bounds__(256, 2) void gemm2_kernel(const ushort_t* __restrict__ g,   // [GS][T][4096]
                                                       const ushort_t* __restrict__ w2t, // [GS][1024][4096]
                                                       const float* __restrict__ b2,     // [E][1024]
                                                       const float* __restrict__ wts,    // [T][8]
                                                       const int* __restrict__ tok,      // [8][T]
                                                       const int* __restrict__ cnts,     // [8]
                                                       float* __restrict__ part,         // [E][T][1024] compacted
                                                       int gbase) {
    const int z = blockIdx.z;
    const int ge = gbase + z;
    const int cnt = cnts[ge];
    const int m0 = blockIdx.y * 128;
    if (m0 >= cnt) return;
    const int n0 = blockIdx.x * 128;

    __shared__ ushort_t sA0[128 * 32], sA1[128 * 32];
    __shared__ ushort_t sB0[128 * 32], sB1[128 * 32];

    const int tid = threadIdx.x;
    const int lane = tid & 63;
    const int wave = tid >> 6;
    const int wr = wave >> 1, wc = wave & 1;

    f32x4 acc[4][4];
#pragma unroll
    for (int i = 0; i < 4; ++i)
#pragma unroll
        for (int j = 0; j < 4; ++j) acc[i][j] = (f32x4)0.f;

    const int rIn = ((lane >> 5) << 3) + (lane & 7);
    const int cIn = (lane >> 3) & 3;

    const ushort_t* ga = g + (size_t)z * TOKENS * D_FF;
    const ushort_t* ap[2];
#pragma unroll
    for (int r = 0; r < 2; ++r) {
        int row = 32 * wave + 16 * r + rIn;
        int i = m0 + row;
        i = (i < cnt) ? i : (cnt - 1);
        ap[r] = ga + (size_t)i * D_FF + cIn * 8;
    }
    const ushort_t* w2e = w2t + (size_t)z * D_MODEL * D_FF;
    const ushort_t* bp[2];
#pragma unroll
    for (int r = 0; r < 2; ++r) {
        int row = 32 * wave + 16 * r + rIn;
        bp[r] = w2e + (size_t)(n0 + row) * D_FF + cIn * 8;
    }

    auto stage = [&](ushort_t* dA, ushort_t* dB, int kk) {
#pragma unroll
        for (int r = 0; r < 2; ++r) {
            gload16(ap[r] + kk, dA + (wave * 2 + r) * 512);
            gload16(bp[r] + kk, dB + (wave * 2 + r) * 512);
        }
    };
    const int c = lane >> 4;
    const int fr = lane & 15;
    auto compute = [&](const ushort_t* pA, const ushort_t* pB) {
        bf16x8 a[4], b[4];
#pragma unroll
        for (int fm = 0; fm < 4; ++fm)
            a[fm] = *reinterpret_cast<const bf16x8*>(&pA[swz(wr * 64 + fm * 16 + fr, c)]);
#pragma unroll
        for (int fn = 0; fn < 4; ++fn)
            b[fn] = *reinterpret_cast<const bf16x8*>(&pB[swz(wc * 64 + fn * 16 + fr, c)]);
#pragma unroll
        for (int fm = 0; fm < 4; ++fm)
#pragma unroll
            for (int fn = 0; fn < 4; ++fn)
                acc[fm][fn] = __builtin_amdgcn_mfma_f32_16x16x32_bf16(a[fm], b[fn], acc[fm][fn], 0, 0, 0);
    };

    // counted-vmcnt pipeline: 128 K-steps (4 loads/stage)
    stage(sA0, sB0, 0);
#pragma unroll 1
    for (int t = 0; t < 126; t += 2) {
        stage(sA1, sB1, (t + 1) * 32);
        VMCNT4(); BAR();
        compute(sA0, sB0);
        BAR();
        stage(sA0, sB0, (t + 2) * 32);
        VMCNT4(); BAR();
        compute(sA1, sB1);
        BAR();
    }
    stage(sA1, sB1, 127 * 32);
    VMCNT4(); BAR();
    compute(sA0, sB0);
    BAR();
    VMCNT0(); BAR();
    compute(sA1, sB1);

    float* pe = part + (size_t)ge * TOKENS * D_MODEL;
#pragma unroll
    for (int fm = 0; fm < 4; ++fm) {
#pragma unroll
        for (int r = 0; r < 4; ++r) {
            int row = m0 + wr * 64 + fm * 16 + (lane >> 4) * 4 + r;
            if (row < cnt) {
                float w = wts[(size_t)tok[ge * TOKENS + row] * 8 + ge];
#pragma unroll
                for (int fn = 0; fn < 4; ++fn) {
                    int col = n0 + wc * 64 + fn * 16 + fr;
                    float bb2 = b2[(size_t)ge * D_MODEL + col];
                    pe[(size_t)row * D_MODEL + col] = (acc[fm][fn][r] + bb2) * w;
                }
            }
        }
    }
}

// ---------------------------------------------------------------- final gather-reduce (one block per token)
__global__ __launch_bounds__(256) void reduce_out_kernel(const float* __restrict__ part, // [E][T][1024]
                                                         const int* __restrict__ pos,    // [T][8]
                                                         float* __restrict__ out) {
    const int t = blockIdx.x;
    const int d = threadIdx.x;   // float4 index, 256*4 = 1024
    float4 s = make_float4(0.f, 0.f, 0.f, 0.f);
#pragma unroll
    for (int e = 0; e < 8; ++e) {
        int p = pos[(size_t)t * 8 + e];
        if (p >= 0) {
            float4 v = reinterpret_cast<const float4*>(part + ((size_t)e * TOKENS + p) * D_MODEL)[d];
            s.x += v.x; s.y += v.y; s.z += v.z; s.w += v.w;
        }
    }
    reinterpret_cast<float4*>(out + (size_t)t * D_MODEL)[d] = s;
}

// ---------------------------------------------------------------- launch
extern "C" void kernel_launch(void* const* d_in, const int* in_sizes, int n_in,
                              void* d_out, int out_size, void* d_ws, size_t ws_size,
                              hipStream_t stream) {
    const float* x  = (const float*)d_in[0];
    const float* Wg = (const float*)d_in[1];
    const float* bg = (const float*)d_in[2];
    const float* W1 = (const float*)d_in[3];
    const float* b1 = (const float*)d_in[4];
    const float* W3 = (const float*)d_in[5];
    const float* b3 = (const float*)d_in[6];
    const float* W2 = (const float*)d_in[7];
    const float* b2 = (const float*)d_in[8];
    float* out = (float*)d_out;

    char* wsb = (char*)d_ws;
    ushort_t* xbf  = (ushort_t*)(wsb);                        // 4 MiB
    float*    wts  = (float*)(wsb + (4u << 20));              // 64 KiB
    float*    probs= (float*)(wsb + (4u << 20) + 65536);      // 64 KiB
    float*    ent  = (float*)(wsb + (4u << 20) + 131072);     // 8 KiB
    int*      tok  = (int*)(wsb + (4u << 20) + 139264);       // 64 KiB
    int*      pos  = (int*)(wsb + (4u << 20) + 204800);       // 64 KiB
    int*      cnts = (int*)(wsb + (4u << 20) + 270336);       // 256 B
    float*    part = (float*)(wsb + (8u << 20));              // 64 MiB ([E][T][1024])

    // per-group buffers after part (ends at 72 MiB)
    const size_t BIG0 = (size_t)72 << 20;
    const size_t PER_E = (size_t)40 << 20;   // w1t+w3t+w2t (24 MB) + gbuf (16 MB)
    int GS = 8;
    if (ws_size < BIG0 + 8 * PER_E) GS = 4;
    if (ws_size < BIG0 + 4 * PER_E) GS = 2;
    if (ws_size < BIG0 + 2 * PER_E) GS = 1;

    char* big = wsb + BIG0;
    const size_t W_SZ = (size_t)GS * ((size_t)D_FF * D_MODEL * 2);   // 8 MiB per expert
    ushort_t* w1t  = (ushort_t*)big;
    ushort_t* w3t  = (ushort_t*)(big + W_SZ);
    ushort_t* w2t  = (ushort_t*)(big + 2 * W_SZ);
    ushort_t* gbuf = (ushort_t*)(big + 3 * W_SZ);

    float* out_scalars = out + FINAL_SIZE;        // [2]
    float* out_act     = out + FINAL_SIZE + 2;    // [TOKENS]

    convert_x_kernel<<<TOKENS * D_MODEL / (256 * 4), 256, 0, stream>>>(x, xbf);
    router_kernel<<<TOKENS / 4, 256, 0, stream>>>(x, Wg, bg, wts, probs, ent, out_act);
    build_lists_kernel<<<1, 512, 0, stream>>>(wts, tok, pos, cnts);
    loss_kernel<<<1, 256, 0, stream>>>(wts, probs, ent, out_scalars);

    for (int g0 = 0; g0 < N_EXP; g0 += GS) {
        wconv_kernel<<<dim3(D_FF / 64, D_MODEL / 32, GS), 256, 0, stream>>>(
            W1 + (size_t)g0 * D_MODEL * D_FF, w1t, D_MODEL, D_FF);
        wconv_kernel<<<dim3(D_FF / 64, D_MODEL / 32, GS), 256, 0, stream>>>(
            W3 + (size_t)g0 * D_MODEL * D_FF, w3t, D_MODEL, D_FF);
        wconv_kernel<<<dim3(D_MODEL / 64, D_FF / 32, GS), 256, 0, stream>>>(
            W2 + (size_t)g0 * D_FF * D_MODEL, w2t, D_FF, D_MODEL);

        gemm1_kernel<<<dim3(D_FF / 64, TOKENS / 128, GS), 256, 0, stream>>>(
            xbf, w1t, w3t, b1, b3, tok, cnts, gbuf, g0);
        gemm2_kernel<<<dim3(D_MODEL / 128, TOKENS / 128, GS), 256, 0, stream>>>(
            gbuf, w2t, b2, wts, tok, cnts, part, g0);
    }
    reduce_out_kernel<<<TOKENS, 256, 0, stream>>>(part, pos, out);
}

// Round 11
// 550.631 us; speedup vs baseline: 1.2456x; 1.2456x over previous
//
#include <hip/hip_runtime.h>
#include <hip/hip_bf16.h>
#include <math.h>

// Problem constants
#define D_MODEL 1024
#define D_FF    4096
#define N_EXP   8
#define TOKENS  2048          // 2 * 1024
#define THRESH  0.8f
#define EPS_R   1e-6f

#define FINAL_SIZE (TOKENS * D_MODEL)   // 2097152

typedef unsigned short ushort_t;
typedef __attribute__((ext_vector_type(4))) float f32x4;
typedef __attribute__((ext_vector_type(8))) short bf16x8;
typedef __attribute__((ext_vector_type(8))) unsigned short ushort8_t;

__device__ __forceinline__ unsigned short f2bf(float f) {
    unsigned u = __builtin_bit_cast(unsigned, f);
    unsigned r = (u + 0x7FFFu + ((u >> 16) & 1u)) >> 16;
    return (unsigned short)r;
}

// async global->LDS, 16B per lane; lds base must be wave-uniform (+lane*16 implicit)
template <typename T>
__device__ __forceinline__ void gload16(const T* gsrc, T* ldst) {
    __builtin_amdgcn_global_load_lds((const __attribute__((address_space(1))) unsigned int*)gsrc,
                                     (__attribute__((address_space(3))) unsigned int*)ldst,
                                     16, 0, 0);
}

// counted-vmcnt pipeline primitives: keep next-tile loads in flight across barriers
#define VMCNT4() asm volatile("s_waitcnt vmcnt(4)" ::: "memory")
#define VMCNT0() asm volatile("s_waitcnt vmcnt(0)" ::: "memory")
#define BAR()    do { __builtin_amdgcn_s_barrier(); asm volatile("" ::: "memory"); } while (0)
#define MFMA(d, x, y) d = __builtin_amdgcn_mfma_f32_16x16x32_bf16(x, y, d, 0, 0, 0)

// ---------------------------------------------------------------- convert x fp32 -> bf16
__global__ __launch_bounds__(256) void convert_x_kernel(const float* __restrict__ x,
                                                        ushort_t* __restrict__ xbf) {
    int i = blockIdx.x * 256 + threadIdx.x;
    const float4 v = reinterpret_cast<const float4*>(x)[i];
    ushort4 o;
    o.x = f2bf(v.x); o.y = f2bf(v.y); o.z = f2bf(v.z); o.w = f2bf(v.w);
    reinterpret_cast<ushort4*>(xbf)[i] = o;
}

// ---------------------------------------------------------------- weight transpose+convert
// in: [K][N] fp32 (expert z at z*K*N), out: [N][K] bf16. Tile 32(k) x 64(n), 256 thr.
__global__ __launch_bounds__(256) void wconv_kernel(const float* __restrict__ in,
                                                    ushort_t* __restrict__ out,
                                                    int K, int N) {
    __shared__ float sT[32][65];
    const int e = blockIdx.z;
    const float* src = in + (size_t)e * K * N;
    ushort_t* dst = out + (size_t)e * K * N;
    const int k0 = blockIdx.y * 32, n0 = blockIdx.x * 64;
    const int t = threadIdx.x;
    {
        const int k = t >> 3;              // 0..31
        const int n4 = (t & 7) * 8;        // 0..56
        const float* s = src + (size_t)(k0 + k) * N + n0 + n4;
        float4 a = *reinterpret_cast<const float4*>(s);
        float4 b = *reinterpret_cast<const float4*>(s + 4);
        sT[k][n4 + 0] = a.x; sT[k][n4 + 1] = a.y; sT[k][n4 + 2] = a.z; sT[k][n4 + 3] = a.w;
        sT[k][n4 + 4] = b.x; sT[k][n4 + 5] = b.y; sT[k][n4 + 6] = b.z; sT[k][n4 + 7] = b.w;
    }
    __syncthreads();
    {
        const int n = t >> 2;              // 0..63
        const int kg = (t & 3) * 8;        // 0..24
        ushort8_t o;
#pragma unroll
        for (int j = 0; j < 8; ++j) o[j] = f2bf(sT[kg + j][n]);
        *reinterpret_cast<ushort8_t*>(dst + (size_t)(n0 + n) * K + k0 + kg) = o;
    }
}

// ---------------------------------------------------------------- router (one wave per token)
__global__ __launch_bounds__(256) void router_kernel(const float* __restrict__ x,
                                                     const float* __restrict__ Wg,
                                                     const float* __restrict__ bg,
                                                     float* __restrict__ wts,     // [T][8]
                                                     float* __restrict__ probs,   // [T][8]
                                                     float* __restrict__ ent,     // [T]
                                                     float* __restrict__ act_out) // [T]
{
    int wave = threadIdx.x >> 6;
    int lane = threadIdx.x & 63;
    int t = blockIdx.x * 4 + wave;

    float acc[8];
#pragma unroll
    for (int e = 0; e < 8; ++e) acc[e] = 0.f;

    const float* xrow = x + (size_t)t * D_MODEL;
    for (int d = lane; d < D_MODEL; d += 64) {
        float xv = xrow[d];
        const float4* wg = reinterpret_cast<const float4*>(Wg + (size_t)d * 8);
        float4 a = wg[0], b = wg[1];
        acc[0] += xv * a.x; acc[1] += xv * a.y; acc[2] += xv * a.z; acc[3] += xv * a.w;
        acc[4] += xv * b.x; acc[5] += xv * b.y; acc[6] += xv * b.z; acc[7] += xv * b.w;
    }
#pragma unroll
    for (int e = 0; e < 8; ++e) {
#pragma unroll
        for (int off = 32; off > 0; off >>= 1) acc[e] += __shfl_xor(acc[e], off);
    }

    if (lane == 0) {
        float l[8], p[8];
        float m = -1e30f;
#pragma unroll
        for (int e = 0; e < 8; ++e) { l[e] = acc[e] + bg[e]; m = fmaxf(m, l[e]); }
        float s = 0.f;
#pragma unroll
        for (int e = 0; e < 8; ++e) { p[e] = expf(l[e] - m); s += p[e]; }
        float inv = 1.f / s;
#pragma unroll
        for (int e = 0; e < 8; ++e) p[e] *= inv;

        int idx[8]; float sp[8];
#pragma unroll
        for (int e = 0; e < 8; ++e) { idx[e] = e; sp[e] = p[e]; }
        for (int i = 0; i < 8; ++i) {
            int best = i;
            for (int j = i + 1; j < 8; ++j) if (sp[j] > sp[best]) best = j;
            float tv = sp[i]; sp[i] = sp[best]; sp[best] = tv;
            int ti = idx[i]; idx[i] = idx[best]; idx[best] = ti;
        }
        float cum = 0.f, asum = 0.f, ap[8];
        int cnt = 0;
        for (int i = 0; i < 8; ++i) {
            int active = (i == 0) || (cum < THRESH);
            cum += sp[i];
            ap[i] = active ? sp[i] : 0.f;
            asum += ap[i];
            cnt += active;
        }
        float rinv = 1.f / (asum + EPS_R);
        float w[8];
        for (int i = 0; i < 8; ++i) w[idx[i]] = ap[i] * rinv;

        float* wrow = wts + (size_t)t * 8;
        float* prow = probs + (size_t)t * 8;
        float e_sum = 0.f;
#pragma unroll
        for (int e = 0; e < 8; ++e) {
            wrow[e] = w[e];
            prow[e] = p[e];
            e_sum -= p[e] * logf(p[e] + EPS_R);
        }
        ent[t] = e_sum;
        act_out[t] = (float)cnt;
    }
}

// ---------------------------------------------------------------- per-expert token compaction
__global__ __launch_bounds__(512) void build_lists_kernel(const float* __restrict__ wts,
                                                          int* __restrict__ tok,   // [8][T]
                                                          int* __restrict__ pos,   // [T][8]
                                                          int* __restrict__ cnt) { // [8]
    const int e = threadIdx.x >> 6;
    const int lane = threadIdx.x & 63;
    int base = 0;
    for (int t0 = 0; t0 < TOKENS; t0 += 64) {
        int t = t0 + lane;
        float w = wts[(size_t)t * 8 + e];
        unsigned long long mask = __ballot(w > 0.f);
        int rank = __popcll(mask & ((1ull << lane) - 1ull));
        if (w > 0.f) {
            tok[e * TOKENS + base + rank] = t;
            pos[(size_t)t * 8 + e] = base + rank;
        } else {
            pos[(size_t)t * 8 + e] = -1;
        }
        base += __popcll(mask);
    }
    if (lane == 0) cnt[e] = base;
}

// ---------------------------------------------------------------- loss reduce (single block, deterministic)
__global__ __launch_bounds__(256) void loss_kernel(const float* __restrict__ wts,
                                                   const float* __restrict__ probs,
                                                   const float* __restrict__ ent,
                                                   float* __restrict__ out_scalars) // [2]
{
    int tid = threadIdx.x;
    float fsum[8], psum[8], es = 0.f;
#pragma unroll
    for (int e = 0; e < 8; ++e) { fsum[e] = 0.f; psum[e] = 0.f; }
    for (int t = tid; t < TOKENS; t += 256) {
        const float* wrow = wts + (size_t)t * 8;
        const float* prow = probs + (size_t)t * 8;
#pragma unroll
        for (int e = 0; e < 8; ++e) {
            fsum[e] += (wrow[e] > 0.f) ? 1.f : 0.f;
            psum[e] += prow[e];
        }
        es += ent[t];
    }
    __shared__ float red[256];
    __shared__ float tot[17];
    for (int q = 0; q < 17; ++q) {
        float v = (q < 8) ? fsum[q] : ((q < 16) ? psum[q - 8] : es);
        red[tid] = v; __syncthreads();
        for (int s = 128; s > 0; s >>= 1) {
            if (tid < s) red[tid] += red[tid + s];
            __syncthreads();
        }
        if (tid == 0) tot[q] = red[0];
        __syncthreads();
    }
    if (tid == 0) {
        const float invT = 1.f / (float)TOKENS;
        float lb = 0.f;
        for (int e = 0; e < 8; ++e) lb += (tot[e] * invT) * (tot[8 + e] * invT);
        out_scalars[0] = 8.f * lb;
        out_scalars[1] = tot[16] * invT;
    }
}

// ---------------------------------------------------------------- GEMM1 (sparse M, phase-split + counted vmcnt + setprio)
// tile 128(M) x 64(N), BK=32, 4 waves (2x2), dual B (W1,W3); LDS 32 KB dbuf
__global__ __launch_bounds__(256, 2) void gemm1_kernel(const ushort_t* __restrict__ xbf, // [T][1024]
                                                       const ushort_t* __restrict__ w1t, // [GS][4096][1024]
                                                       const ushort_t* __restrict__ w3t,
                                                       const float* __restrict__ b1,     // [E][4096]
                                                       const float* __restrict__ b3,
                                                       const int* __restrict__ tok,      // [8][T]
                                                       const int* __restrict__ cnts,     // [8]
                                                       ushort_t* __restrict__ g,         // [GS][T][4096] compacted
                                                       int gbase) {
    const int z = blockIdx.z;
    const int ge = gbase + z;
    const int cnt = cnts[ge];

    // XCD swizzle: each XCD owns a contiguous chunk of 8 N-tiles
    const int NX = D_FF / 64;          // 64
    const int CHUNK = NX / 8;          // 8
    const int orig = blockIdx.x + NX * blockIdx.y;
    const int inner = orig >> 3;
    const int nx = (orig & 7) * CHUNK + (inner & (CHUNK - 1));
    const int ny = inner / CHUNK;      // 0..15
    const int m0 = ny * 128;
    const int n0 = nx * 64;
    if (m0 >= cnt) return;

    __shared__ ushort_t sA0[128 * 32], sA1[128 * 32];
    __shared__ ushort_t sB10[64 * 32], sB11[64 * 32];
    __shared__ ushort_t sB30[64 * 32], sB31[64 * 32];

    const int tid = threadIdx.x;
    const int lane = tid & 63;
    const int wave = tid >> 6;
    const int wr = wave >> 1, wc = wave & 1;

    f32x4 acc1[4][2], acc3[4][2];
#pragma unroll
    for (int i = 0; i < 4; ++i)
#pragma unroll
        for (int j = 0; j < 2; ++j) { acc1[i][j] = (f32x4)0.f; acc3[i][j] = (f32x4)0.f; }

    const int srow = tid >> 2;        // 0..63 (row within staging round)
    const int scol = (tid & 3) * 8;   // bf16 col within 32-wide K slice

    // indirect A row base pointers (token gather), clamped for tail tiles
    const ushort_t* abase[2];
#pragma unroll
    for (int r = 0; r < 2; ++r) {
        int i = m0 + srow + r * 64;
        i = (i < cnt) ? i : (cnt - 1);
        abase[r] = xbf + (size_t)tok[ge * TOKENS + i] * D_MODEL + scol;
    }
    const ushort_t* w1p = w1t + (size_t)z * D_FF * D_MODEL + (size_t)(n0 + srow) * D_MODEL + scol;
    const ushort_t* w3p = w3t + (size_t)z * D_FF * D_MODEL + (size_t)(n0 + srow) * D_MODEL + scol;

    auto stage = [&](ushort_t* dA, ushort_t* dB1, ushort_t* dB3, int kk) {
        gload16(abase[0] + kk, dA + wave * 512);
        gload16(abase[1] + kk, dA + 2048 + wave * 512);
        gload16(w1p + kk, dB1 + wave * 512);
        gload16(w3p + kk, dB3 + wave * 512);
    };

    const int ko = (lane >> 4) * 8;
    const int fr = lane & 15;

    stage(sA0, sB10, sB30, 0);
#pragma unroll 1
    for (int t = 0; t < 32; ++t) {
        const int p = t & 1;
        ushort_t* A  = p ? sA1  : sA0;
        ushort_t* B1 = p ? sB11 : sB10;
        ushort_t* B3 = p ? sB31 : sB30;
        if (t + 1 < 32) {
            stage(p ? sA0 : sA1, p ? sB10 : sB11, p ? sB30 : sB31, (t + 1) * 32);
            VMCNT4();           // this buffer's 4 loads done; next-tile 4 stay in flight
        } else {
            VMCNT0();
        }
        BAR();                  // all waves' loads for this buffer complete

        // phase A: B-frags + a0,a1 -> 8 MFMA
        bf16x8 u10 = *reinterpret_cast<const bf16x8*>(&B1[(wc * 32 + fr) * 32 + ko]);
        bf16x8 u11 = *reinterpret_cast<const bf16x8*>(&B1[(wc * 32 + 16 + fr) * 32 + ko]);
        bf16x8 u30 = *reinterpret_cast<const bf16x8*>(&B3[(wc * 32 + fr) * 32 + ko]);
        bf16x8 u31 = *reinterpret_cast<const bf16x8*>(&B3[(wc * 32 + 16 + fr) * 32 + ko]);
        bf16x8 a0 = *reinterpret_cast<const bf16x8*>(&A[(wr * 64 + fr) * 32 + ko]);
        bf16x8 a1 = *reinterpret_cast<const bf16x8*>(&A[(wr * 64 + 16 + fr) * 32 + ko]);
        __builtin_amdgcn_s_setprio(1);
        MFMA(acc1[0][0], a0, u10); MFMA(acc1[0][1], a0, u11);
        MFMA(acc3[0][0], a0, u30); MFMA(acc3[0][1], a0, u31);
        MFMA(acc1[1][0], a1, u10); MFMA(acc1[1][1], a1, u11);
        MFMA(acc3[1][0], a1, u30); MFMA(acc3[1][1], a1, u31);
        __builtin_amdgcn_s_setprio(0);
        BAR();                  // phase boundary: stagger blocks' roles on the CU

        // phase B: a2,a3 -> 8 MFMA
        bf16x8 a2 = *reinterpret_cast<const bf16x8*>(&A[(wr * 64 + 32 + fr) * 32 + ko]);
        bf16x8 a3 = *reinterpret_cast<const bf16x8*>(&A[(wr * 64 + 48 + fr) * 32 + ko]);
        __builtin_amdgcn_s_setprio(1);
        MFMA(acc1[2][0], a2, u10); MFMA(acc1[2][1], a2, u11);
        MFMA(acc3[2][0], a2, u30); MFMA(acc3[2][1], a2, u31);
        MFMA(acc1[3][0], a3, u10); MFMA(acc1[3][1], a3, u11);
        MFMA(acc3[3][0], a3, u30); MFMA(acc3[3][1], a3, u31);
        __builtin_amdgcn_s_setprio(0);
        BAR();                  // all reads of this buffer done -> next iter may overwrite
    }

    // epilogue: SwiGLU -> bf16 g (compacted rows, guarded)
    ushort_t* ge_out = g + (size_t)z * TOKENS * D_FF;
#pragma unroll
    for (int fn = 0; fn < 2; ++fn) {
        int col = n0 + wc * 32 + fn * 16 + fr;
        float bb1 = b1[(size_t)ge * D_FF + col];
        float bb3 = b3[(size_t)ge * D_FF + col];
#pragma unroll
        for (int fm = 0; fm < 4; ++fm) {
#pragma unroll
            for (int r = 0; r < 4; ++r) {
                int row = m0 + wr * 64 + fm * 16 + (lane >> 4) * 4 + r;
                if (row < cnt) {
                    float h1 = acc1[fm][fn][r] + bb1;
                    float h3 = acc3[fm][fn][r] + bb3;
                    float gv = (h1 / (1.f + expf(-h1))) * h3;
                    ge_out[(size_t)row * D_FF + col] = f2bf(gv);
                }
            }
        }
    }
}

// ---------------------------------------------------------------- GEMM2 (sparse M, phase-split + counted vmcnt + setprio)
// tile 128(M) x 128(N), BK=32, 4 waves (2x2, wave 64x64); LDS 32 KB dbuf
__global__ __launch_bounds__(256, 2) void gemm2_kernel(const ushort_t* __restrict__ g,   // [GS][T][4096]
                                                       const ushort_t* __restrict__ w2t, // [GS][1024][4096]
                                                       const float* __restrict__ b2,     // [E][1024]
                                                       const float* __restrict__ wts,    // [T][8]
                                                       const int* __restrict__ tok,      // [8][T]
                                                       const int* __restrict__ cnts,     // [8]
                                                       float* __restrict__ part,         // [E][T][1024] compacted
                                                       int gbase) {
    const int z = blockIdx.z;
    const int ge = gbase + z;
    const int cnt = cnts[ge];
    const int m0 = blockIdx.y * 128;
    if (m0 >= cnt) return;
    const int n0 = blockIdx.x * 128;

    __shared__ ushort_t sA0[128 * 32], sA1[128 * 32];
    __shared__ ushort_t sB0[128 * 32], sB1[128 * 32];

    const int tid = threadIdx.x;
    const int lane = tid & 63;
    const int wave = tid >> 6;
    const int wr = wave >> 1, wc = wave & 1;

    f32x4 acc[4][4];
#pragma unroll
    for (int i = 0; i < 4; ++i)
#pragma unroll
        for (int j = 0; j < 4; ++j) acc[i][j] = (f32x4)0.f;

    const int srow = tid >> 2;        // 0..63
    const int scol = (tid & 3) * 8;

    const ushort_t* ga = g + (size_t)z * TOKENS * D_FF;
    const ushort_t* ap[2];
#pragma unroll
    for (int r = 0; r < 2; ++r) {
        int i = m0 + r * 64 + srow;
        i = (i < cnt) ? i : (cnt - 1);
        ap[r] = ga + (size_t)i * D_FF + scol;
    }
    const ushort_t* w2e = w2t + (size_t)z * D_MODEL * D_FF;
    const ushort_t* bp[2];
#pragma unroll
    for (int r = 0; r < 2; ++r)
        bp[r] = w2e + (size_t)(n0 + r * 64 + srow) * D_FF + scol;

    auto stage = [&](ushort_t* dA, ushort_t* dB, int kk) {
#pragma unroll
        for (int r = 0; r < 2; ++r) {
            gload16(ap[r] + kk, dA + r * 2048 + wave * 512);
            gload16(bp[r] + kk, dB + r * 2048 + wave * 512);
        }
    };

    const int ko = (lane >> 4) * 8;
    const int fr = lane & 15;

    stage(sA0, sB0, 0);
#pragma unroll 1
    for (int t = 0; t < 128; ++t) {
        const int p = t & 1;
        ushort_t* A = p ? sA1 : sA0;
        ushort_t* B = p ? sB1 : sB0;
        if (t + 1 < 128) {
            stage(p ? sA0 : sA1, p ? sB0 : sB1, (t + 1) * 32);
            VMCNT4();
        } else {
            VMCNT0();
        }
        BAR();

        // phase A: b0..b3 + a0,a1 -> 8 MFMA
        bf16x8 b0 = *reinterpret_cast<const bf16x8*>(&B[(wc * 64 + fr) * 32 + ko]);
        bf16x8 b1f = *reinterpret_cast<const bf16x8*>(&B[(wc * 64 + 16 + fr) * 32 + ko]);
        bf16x8 b2f = *reinterpret_cast<const bf16x8*>(&B[(wc * 64 + 32 + fr) * 32 + ko]);
        bf16x8 b3f = *reinterpret_cast<const bf16x8*>(&B[(wc * 64 + 48 + fr) * 32 + ko]);
        bf16x8 a0 = *reinterpret_cast<const bf16x8*>(&A[(wr * 64 + fr) * 32 + ko]);
        bf16x8 a1 = *reinterpret_cast<const bf16x8*>(&A[(wr * 64 + 16 + fr) * 32 + ko]);
        __builtin_amdgcn_s_setprio(1);
        MFMA(acc[0][0], a0, b0); MFMA(acc[0][1], a0, b1f);
        MFMA(acc[0][2], a0, b2f); MFMA(acc[0][3], a0, b3f);
        MFMA(acc[1][0], a1, b0); MFMA(acc[1][1], a1, b1f);
        MFMA(acc[1][2], a1, b2f); MFMA(acc[1][3], a1, b3f);
        __builtin_amdgcn_s_setprio(0);
        BAR();

        // phase B: a2,a3 -> 8 MFMA
        bf16x8 a2 = *reinterpret_cast<const bf16x8*>(&A[(wr * 64 + 32 + fr) * 32 + ko]);
        bf16x8 a3 = *reinterpret_cast<const bf16x8*>(&A[(wr * 64 + 48 + fr) * 32 + ko]);
        __builtin_amdgcn_s_setprio(1);
        MFMA(acc[2][0], a2, b0); MFMA(acc[2][1], a2, b1f);
        MFMA(acc[2][2], a2, b2f); MFMA(acc[2][3], a2, b3f);
        MFMA(acc[3][0], a3, b0); MFMA(acc[3][1], a3, b1f);
        MFMA(acc[3][2], a3, b2f); MFMA(acc[3][3], a3, b3f);
        __builtin_amdgcn_s_setprio(0);
        BAR();
    }

    float* pe = part + (size_t)ge * TOKENS * D_MODEL;
#pragma unroll
    for (int fm = 0; fm < 4; ++fm) {
#pragma unroll
        for (int r = 0; r < 4; ++r) {
            int row = m0 + wr * 64 + fm * 16 + (lane >> 4) * 4 + r;
            if (row < cnt) {
                float w = wts[(size_t)tok[ge * TOKENS + row] * 8 + ge];
#pragma unroll
                for (int fn = 0; fn < 4; ++fn) {
                    int col = n0 + wc * 64 + fn * 16 + fr;
                    float bb2 = b2[(size_t)ge * D_MODEL + col];
                    pe[(size_t)row * D_MODEL + col] = (acc[fm][fn][r] + bb2) * w;
                }
            }
        }
    }
}

// ---------------------------------------------------------------- final gather-reduce (one block per token)
__global__ __launch_bounds__(256) void reduce_out_kernel(const float* __restrict__ part, // [E][T][1024]
                                                         const int* __restrict__ pos,    // [T][8]
                                                         float* __restrict__ out) {
    const int t = blockIdx.x;
    const int d = threadIdx.x;   // float4 index, 256*4 = 1024
    float4 s = make_float4(0.f, 0.f, 0.f, 0.f);
#pragma unroll
    for (int e = 0; e < 8; ++e) {
        int p = pos[(size_t)t * 8 + e];
        if (p >= 0) {
            float4 v = reinterpret_cast<const float4*>(part + ((size_t)e * TOKENS + p) * D_MODEL)[d];
            s.x += v.x; s.y += v.y; s.z += v.z; s.w += v.w;
        }
    }
    reinterpret_cast<float4*>(out + (size_t)t * D_MODEL)[d] = s;
}

// ---------------------------------------------------------------- launch
extern "C" void kernel_launch(void* const* d_in, const int* in_sizes, int n_in,
                              void* d_out, int out_size, void* d_ws, size_t ws_size,
                              hipStream_t stream) {
    const float* x  = (const float*)d_in[0];
    const float* Wg = (const float*)d_in[1];
    const float* bg = (const float*)d_in[2];
    const float* W1 = (const float*)d_in[3];
    const float* b1 = (const float*)d_in[4];
    const float* W3 = (const float*)d_in[5];
    const float* b3 = (const float*)d_in[6];
    const float* W2 = (const float*)d_in[7];
    const float* b2 = (const float*)d_in[8];
    float* out = (float*)d_out;

    char* wsb = (char*)d_ws;
    ushort_t* xbf  = (ushort_t*)(wsb);                        // 4 MiB
    float*    wts  = (float*)(wsb + (4u << 20));              // 64 KiB
    float*    probs= (float*)(wsb + (4u << 20) + 65536);      // 64 KiB
    float*    ent  = (float*)(wsb + (4u << 20) + 131072);     // 8 KiB
    int*      tok  = (int*)(wsb + (4u << 20) + 139264);       // 64 KiB
    int*      pos  = (int*)(wsb + (4u << 20) + 204800);       // 64 KiB
    int*      cnts = (int*)(wsb + (4u << 20) + 270336);       // 256 B
    float*    part = (float*)(wsb + (8u << 20));              // 64 MiB ([E][T][1024])

    // per-group buffers after part (ends at 72 MiB)
    const size_t BIG0 = (size_t)72 << 20;
    const size_t PER_E = (size_t)40 << 20;   // w1t+w3t+w2t (24 MB) + gbuf (16 MB)
    int GS = 8;
    if (ws_size < BIG0 + 8 * PER_E) GS = 4;
    if (ws_size < BIG0 + 4 * PER_E) GS = 2;
    if (ws_size < BIG0 + 2 * PER_E) GS = 1;

    char* big = wsb + BIG0;
    const size_t W_SZ = (size_t)GS * ((size_t)D_FF * D_MODEL * 2);   // 8 MiB per expert
    ushort_t* w1t  = (ushort_t*)big;
    ushort_t* w3t  = (ushort_t*)(big + W_SZ);
    ushort_t* w2t  = (ushort_t*)(big + 2 * W_SZ);
    ushort_t* gbuf = (ushort_t*)(big + 3 * W_SZ);

    float* out_scalars = out + FINAL_SIZE;        // [2]
    float* out_act     = out + FINAL_SIZE + 2;    // [TOKENS]

    convert_x_kernel<<<TOKENS * D_MODEL / (256 * 4), 256, 0, stream>>>(x, xbf);
    router_kernel<<<TOKENS / 4, 256, 0, stream>>>(x, Wg, bg, wts, probs, ent, out_act);
    build_lists_kernel<<<1, 512, 0, stream>>>(wts, tok, pos, cnts);
    loss_kernel<<<1, 256, 0, stream>>>(wts, probs, ent, out_scalars);

    for (int g0 = 0; g0 < N_EXP; g0 += GS) {
        wconv_kernel<<<dim3(D_FF / 64, D_MODEL / 32, GS), 256, 0, stream>>>(
            W1 + (size_t)g0 * D_MODEL * D_FF, w1t, D_MODEL, D_FF);
        wconv_kernel<<<dim3(D_FF / 64, D_MODEL / 32, GS), 256, 0, stream>>>(
            W3 + (size_t)g0 * D_MODEL * D_FF, w3t, D_MODEL, D_FF);
        wconv_kernel<<<dim3(D_MODEL / 64, D_FF / 32, GS), 256, 0, stream>>>(
            W2 + (size_t)g0 * D_FF * D_MODEL, w2t, D_FF, D_MODEL);

        gemm1_kernel<<<dim3(D_FF / 64, TOKENS / 128, GS), 256, 0, stream>>>(
            xbf, w1t, w3t, b1, b3, tok, cnts, gbuf, g0);
        gemm2_kernel<<<dim3(D_MODEL / 128, TOKENS / 128, GS), 256, 0, stream>>>(
            gbuf, w2t, b2, wts, tok, cnts, part, g0);
    }
    reduce_out_kernel<<<TOKENS, 256, 0, stream>>>(part, pos, out);
}

// Round 12
// 530.370 us; speedup vs baseline: 1.2932x; 1.0382x over previous
//
#include <hip/hip_runtime.h>
#include <hip/hip_bf16.h>
#include <math.h>

// Problem constants
#define D_MODEL 1024
#define D_FF    4096
#define N_EXP   8
#define TOKENS  2048          // 2 * 1024
#define THRESH  0.8f
#define EPS_R   1e-6f

#define FINAL_SIZE (TOKENS * D_MODEL)   // 2097152

typedef unsigned short ushort_t;
typedef __attribute__((ext_vector_type(4))) float f32x4;
typedef __attribute__((ext_vector_type(8))) short bf16x8;
typedef __attribute__((ext_vector_type(8))) unsigned short ushort8_t;

__device__ __forceinline__ unsigned short f2bf(float f) {
    unsigned u = __builtin_bit_cast(unsigned, f);
    unsigned r = (u + 0x7FFFu + ((u >> 16) & 1u)) >> 16;
    return (unsigned short)r;
}

// async global->LDS, 16B per lane; lds base must be wave-uniform (+lane*16 implicit)
template <typename T>
__device__ __forceinline__ void gload16(const T* gsrc, T* ldst) {
    __builtin_amdgcn_global_load_lds((const __attribute__((address_space(1))) unsigned int*)gsrc,
                                     (__attribute__((address_space(3))) unsigned int*)ldst,
                                     16, 0, 0);
}

// counted-vmcnt pipeline primitives: keep future-tile loads in flight across barriers
#define VMCNT8() asm volatile("s_waitcnt vmcnt(8)" ::: "memory")
#define VMCNT4() asm volatile("s_waitcnt vmcnt(4)" ::: "memory")
#define VMCNT0() asm volatile("s_waitcnt vmcnt(0)" ::: "memory")
#define BAR()    do { __builtin_amdgcn_s_barrier(); asm volatile("" ::: "memory"); } while (0)

// ---------------------------------------------------------------- convert x fp32 -> bf16
__global__ __launch_bounds__(256) void convert_x_kernel(const float* __restrict__ x,
                                                        ushort_t* __restrict__ xbf) {
    int i = blockIdx.x * 256 + threadIdx.x;
    const float4 v = reinterpret_cast<const float4*>(x)[i];
    ushort4 o;
    o.x = f2bf(v.x); o.y = f2bf(v.y); o.z = f2bf(v.z); o.w = f2bf(v.w);
    reinterpret_cast<ushort4*>(xbf)[i] = o;
}

// ---------------------------------------------------------------- weight transpose+convert
// in: [K][N] fp32 (expert z at z*K*N), out: [N][K] bf16. Tile 64(k) x 64(n), 256 thr.
// 64-deep k gives each n-row a full 128B cacheline write (no write amplification).
__global__ __launch_bounds__(256) void wconv_kernel(const float* __restrict__ in,
                                                    ushort_t* __restrict__ out,
                                                    int K, int N) {
    __shared__ float sT[64][65];   // 16.6 KB, +1 pad
    const int e = blockIdx.z;
    const float* src = in + (size_t)e * K * N;
    ushort_t* dst = out + (size_t)e * K * N;
    const int k0 = blockIdx.y * 64, n0 = blockIdx.x * 64;
    const int t = threadIdx.x;
    {
        const int k = t >> 2;              // 0..63
        const int c = (t & 3) * 16;        // 0,16,32,48
        const float* s = src + (size_t)(k0 + k) * N + n0 + c;
#pragma unroll
        for (int j = 0; j < 4; ++j) {
            float4 v = *reinterpret_cast<const float4*>(s + 4 * j);
            sT[k][c + 4 * j + 0] = v.x; sT[k][c + 4 * j + 1] = v.y;
            sT[k][c + 4 * j + 2] = v.z; sT[k][c + 4 * j + 3] = v.w;
        }
    }
    __syncthreads();
    {
        const int n = t >> 2;              // 0..63
        const int ks = (t & 3) * 16;       // 0,16,32,48
        ushort_t* d = dst + (size_t)(n0 + n) * K + k0 + ks;
#pragma unroll
        for (int h = 0; h < 2; ++h) {
            ushort8_t o;
#pragma unroll
            for (int j = 0; j < 8; ++j) o[j] = f2bf(sT[ks + h * 8 + j][n]);
            *reinterpret_cast<ushort8_t*>(d + h * 8) = o;
        }
    }
}

// ---------------------------------------------------------------- router (one wave per token)
__global__ __launch_bounds__(256) void router_kernel(const float* __restrict__ x,
                                                     const float* __restrict__ Wg,
                                                     const float* __restrict__ bg,
                                                     float* __restrict__ wts,     // [T][8]
                                                     float* __restrict__ probs,   // [T][8]
                                                     float* __restrict__ ent,     // [T]
                                                     float* __restrict__ act_out) // [T]
{
    int wave = threadIdx.x >> 6;
    int lane = threadIdx.x & 63;
    int t = blockIdx.x * 4 + wave;

    float acc[8];
#pragma unroll
    for (int e = 0; e < 8; ++e) acc[e] = 0.f;

    const float* xrow = x + (size_t)t * D_MODEL;
    for (int d = lane; d < D_MODEL; d += 64) {
        float xv = xrow[d];
        const float4* wg = reinterpret_cast<const float4*>(Wg + (size_t)d * 8);
        float4 a = wg[0], b = wg[1];
        acc[0] += xv * a.x; acc[1] += xv * a.y; acc[2] += xv * a.z; acc[3] += xv * a.w;
        acc[4] += xv * b.x; acc[5] += xv * b.y; acc[6] += xv * b.z; acc[7] += xv * b.w;
    }
#pragma unroll
    for (int e = 0; e < 8; ++e) {
#pragma unroll
        for (int off = 32; off > 0; off >>= 1) acc[e] += __shfl_xor(acc[e], off);
    }

    if (lane == 0) {
        float l[8], p[8];
        float m = -1e30f;
#pragma unroll
        for (int e = 0; e < 8; ++e) { l[e] = acc[e] + bg[e]; m = fmaxf(m, l[e]); }
        float s = 0.f;
#pragma unroll
        for (int e = 0; e < 8; ++e) { p[e] = expf(l[e] - m); s += p[e]; }
        float inv = 1.f / s;
#pragma unroll
        for (int e = 0; e < 8; ++e) p[e] *= inv;

        int idx[8]; float sp[8];
#pragma unroll
        for (int e = 0; e < 8; ++e) { idx[e] = e; sp[e] = p[e]; }
        for (int i = 0; i < 8; ++i) {
            int best = i;
            for (int j = i + 1; j < 8; ++j) if (sp[j] > sp[best]) best = j;
            float tv = sp[i]; sp[i] = sp[best]; sp[best] = tv;
            int ti = idx[i]; idx[i] = idx[best]; idx[best] = ti;
        }
        float cum = 0.f, asum = 0.f, ap[8];
        int cnt = 0;
        for (int i = 0; i < 8; ++i) {
            int active = (i == 0) || (cum < THRESH);
            cum += sp[i];
            ap[i] = active ? sp[i] : 0.f;
            asum += ap[i];
            cnt += active;
        }
        float rinv = 1.f / (asum + EPS_R);
        float w[8];
        for (int i = 0; i < 8; ++i) w[idx[i]] = ap[i] * rinv;

        float* wrow = wts + (size_t)t * 8;
        float* prow = probs + (size_t)t * 8;
        float e_sum = 0.f;
#pragma unroll
        for (int e = 0; e < 8; ++e) {
            wrow[e] = w[e];
            prow[e] = p[e];
            e_sum -= p[e] * logf(p[e] + EPS_R);
        }
        ent[t] = e_sum;
        act_out[t] = (float)cnt;
    }
}

// ---------------------------------------------------------------- per-expert token compaction
__global__ __launch_bounds__(512) void build_lists_kernel(const float* __restrict__ wts,
                                                          int* __restrict__ tok,   // [8][T]
                                                          int* __restrict__ pos,   // [T][8]
                                                          int* __restrict__ cnt) { // [8]
    const int e = threadIdx.x >> 6;
    const int lane = threadIdx.x & 63;
    int base = 0;
    for (int t0 = 0; t0 < TOKENS; t0 += 64) {
        int t = t0 + lane;
        float w = wts[(size_t)t * 8 + e];
        unsigned long long mask = __ballot(w > 0.f);
        int rank = __popcll(mask & ((1ull << lane) - 1ull));
        if (w > 0.f) {
            tok[e * TOKENS + base + rank] = t;
            pos[(size_t)t * 8 + e] = base + rank;
        } else {
            pos[(size_t)t * 8 + e] = -1;
        }
        base += __popcll(mask);
    }
    if (lane == 0) cnt[e] = base;
}

// ---------------------------------------------------------------- loss reduce (single block, deterministic)
__global__ __launch_bounds__(256) void loss_kernel(const float* __restrict__ wts,
                                                   const float* __restrict__ probs,
                                                   const float* __restrict__ ent,
                                                   float* __restrict__ out_scalars) // [2]
{
    int tid = threadIdx.x;
    float fsum[8], psum[8], es = 0.f;
#pragma unroll
    for (int e = 0; e < 8; ++e) { fsum[e] = 0.f; psum[e] = 0.f; }
    for (int t = tid; t < TOKENS; t += 256) {
        const float* wrow = wts + (size_t)t * 8;
        const float* prow = probs + (size_t)t * 8;
#pragma unroll
        for (int e = 0; e < 8; ++e) {
            fsum[e] += (wrow[e] > 0.f) ? 1.f : 0.f;
            psum[e] += prow[e];
        }
        es += ent[t];
    }
    __shared__ float red[256];
    __shared__ float tot[17];
    for (int q = 0; q < 17; ++q) {
        float v = (q < 8) ? fsum[q] : ((q < 16) ? psum[q - 8] : es);
        red[tid] = v; __syncthreads();
        for (int s = 128; s > 0; s >>= 1) {
            if (tid < s) red[tid] += red[tid + s];
            __syncthreads();
        }
        if (tid == 0) tot[q] = red[0];
        __syncthreads();
    }
    if (tid == 0) {
        const float invT = 1.f / (float)TOKENS;
        float lb = 0.f;
        for (int e = 0; e < 8; ++e) lb += (tot[e] * invT) * (tot[8 + e] * invT);
        out_scalars[0] = 8.f * lb;
        out_scalars[1] = tot[16] * invT;
    }
}

// ---------------------------------------------------------------- GEMM1 (sparse M, depth-2 prefetch, counted vmcnt)
// tile 128(M) x 64(N), BK=32, 4 waves (2x2), dual B (W1,W3); LDS 3x16 KB triple-buffer
__global__ __launch_bounds__(256, 2) void gemm1_kernel(const ushort_t* __restrict__ xbf, // [T][1024]
                                                       const ushort_t* __restrict__ w1t, // [GS][4096][1024]
                                                       const ushort_t* __restrict__ w3t,
                                                       const float* __restrict__ b1,     // [E][4096]
                                                       const float* __restrict__ b3,
                                                       const int* __restrict__ tok,      // [8][T]
                                                       const int* __restrict__ cnts,     // [8]
                                                       ushort_t* __restrict__ g,         // [GS][T][4096] compacted
                                                       int gbase) {
    const int z = blockIdx.z;
    const int ge = gbase + z;
    const int cnt = cnts[ge];

    // XCD swizzle: each XCD owns a contiguous chunk of 8 N-tiles
    const int NX = D_FF / 64;          // 64
    const int CHUNK = NX / 8;          // 8
    const int orig = blockIdx.x + NX * blockIdx.y;
    const int inner = orig >> 3;
    const int nx = (orig & 7) * CHUNK + (inner & (CHUNK - 1));
    const int ny = inner / CHUNK;      // 0..15
    const int m0 = ny * 128;
    const int n0 = nx * 64;
    if (m0 >= cnt) return;

    __shared__ ushort_t sA[3][128 * 32];
    __shared__ ushort_t sB1[3][64 * 32];
    __shared__ ushort_t sB3[3][64 * 32];

    const int tid = threadIdx.x;
    const int lane = tid & 63;
    const int wave = tid >> 6;
    const int wr = wave >> 1, wc = wave & 1;

    f32x4 acc1[4][2], acc3[4][2];
#pragma unroll
    for (int i = 0; i < 4; ++i)
#pragma unroll
        for (int j = 0; j < 2; ++j) { acc1[i][j] = (f32x4)0.f; acc3[i][j] = (f32x4)0.f; }

    const int srow = tid >> 2;        // 0..63 (row within staging round)
    const int scol = (tid & 3) * 8;   // bf16 col within 32-wide K slice

    // indirect A row base pointers (token gather), clamped for tail tiles
    const ushort_t* abase[2];
#pragma unroll
    for (int r = 0; r < 2; ++r) {
        int i = m0 + srow + r * 64;
        i = (i < cnt) ? i : (cnt - 1);
        abase[r] = xbf + (size_t)tok[ge * TOKENS + i] * D_MODEL + scol;
    }
    const ushort_t* w1p = w1t + (size_t)z * D_FF * D_MODEL + (size_t)(n0 + srow) * D_MODEL + scol;
    const ushort_t* w3p = w3t + (size_t)z * D_FF * D_MODEL + (size_t)(n0 + srow) * D_MODEL + scol;

    auto stage = [&](int b, int kk) {
        gload16(abase[0] + kk, &sA[b][0] + wave * 512);
        gload16(abase[1] + kk, &sA[b][0] + 2048 + wave * 512);
        gload16(w1p + kk, &sB1[b][0] + wave * 512);
        gload16(w3p + kk, &sB3[b][0] + wave * 512);
    };
    auto compute = [&](int b) {
        const int ko = (lane >> 4) * 8;
        const int fr = lane & 15;
        bf16x8 a[4], u1[2], u3[2];
#pragma unroll
        for (int fm = 0; fm < 4; ++fm)
            a[fm] = *reinterpret_cast<const bf16x8*>(&sA[b][(wr * 64 + fm * 16 + fr) * 32 + ko]);
#pragma unroll
        for (int fn = 0; fn < 2; ++fn) {
            u1[fn] = *reinterpret_cast<const bf16x8*>(&sB1[b][(wc * 32 + fn * 16 + fr) * 32 + ko]);
            u3[fn] = *reinterpret_cast<const bf16x8*>(&sB3[b][(wc * 32 + fn * 16 + fr) * 32 + ko]);
        }
#pragma unroll
        for (int fm = 0; fm < 4; ++fm)
#pragma unroll
            for (int fn = 0; fn < 2; ++fn) {
                acc1[fm][fn] = __builtin_amdgcn_mfma_f32_16x16x32_bf16(a[fm], u1[fn], acc1[fm][fn], 0, 0, 0);
                acc3[fm][fn] = __builtin_amdgcn_mfma_f32_16x16x32_bf16(a[fm], u3[fn], acc3[fm][fn], 0, 0, 0);
            }
    };

    // depth-2 pipeline: buffers (t)%3; loads for t+1, t+2 stay in flight during compute(t)
    stage(0, 0);
    stage(1, 32);
#pragma unroll 1
    for (int t = 0; t < 32; ++t) {
        if (t + 2 < 32) {
            stage((t + 2) % 3, (t + 2) * 32);
            VMCNT8();          // buf t done; t+1 (4) and t+2 (4) remain in flight
        } else if (t + 1 < 32) {
            VMCNT4();          // only t+1's 4 remain
        } else {
            VMCNT0();
        }
        BAR();                 // all waves see buf t complete
        compute(t % 3);
        BAR();                 // reads of buf t done -> (t+3) may overwrite at t+1
    }

    // epilogue: SwiGLU -> bf16 g (compacted rows, guarded)
    ushort_t* ge_out = g + (size_t)z * TOKENS * D_FF;
#pragma unroll
    for (int fn = 0; fn < 2; ++fn) {
        int col = n0 + wc * 32 + fn * 16 + (lane & 15);
        float bb1 = b1[(size_t)ge * D_FF + col];
        float bb3 = b3[(size_t)ge * D_FF + col];
#pragma unroll
        for (int fm = 0; fm < 4; ++fm) {
#pragma unroll
            for (int r = 0; r < 4; ++r) {
                int row = m0 + wr * 64 + fm * 16 + (lane >> 4) * 4 + r;
                if (row < cnt) {
                    float h1 = acc1[fm][fn][r] + bb1;
                    float h3 = acc3[fm][fn][r] + bb3;
                    float gv = (h1 / (1.f + expf(-h1))) * h3;
                    ge_out[(size_t)row * D_FF + col] = f2bf(gv);
                }
            }
        }
    }
}

// ---------------------------------------------------------------- GEMM2 (sparse M, counted-vmcnt dbuf) [r9-proven]
// tile 128(M) x 128(N), BK=32, 4 waves (2x2, wave 64x64); LDS 32 KB dbuf
__global__ __launch_bounds__(256, 2) void gemm2_kernel(const ushort_t* __restrict__ g,   // [GS][T][4096]
                                                       const ushort_t* __restrict__ w2t, // [GS][1024][4096]
                                                       const float* __restrict__ b2,     // [E][1024]
                                                       const float* __restrict__ wts,    // [T][8]
                                                       const int* __restrict__ tok,      // [8][T]
                                                       const int* __restrict__ cnts,     // [8]
                                                       float* __restrict__ part,         // [E][T][1024] compacted
                                                       int gbase) {
    const int z = blockIdx.z;
    const int ge = gbase + z;
    const int cnt = cnts[ge];
    const int m0 = blockIdx.y * 128;
    if (m0 >= cnt) return;
    const int n0 = blockIdx.x * 128;

    __shared__ ushort_t sA0[128 * 32], sA1[128 * 32];
    __shared__ ushort_t sB0[128 * 32], sB1[128 * 32];

    const int tid = threadIdx.x;
    const int lane = tid & 63;
    const int wave = tid >> 6;
    const int wr = wave >> 1, wc = wave & 1;

    f32x4 acc[4][4];
#pragma unroll
    for (int i = 0; i < 4; ++i)
#pragma unroll
        for (int j = 0; j < 4; ++j) acc[i][j] = (f32x4)0.f;

    const int srow = tid >> 2;        // 0..63
    const int scol = (tid & 3) * 8;

    const ushort_t* ga = g + (size_t)z * TOKENS * D_FF;
    const ushort_t* ap[2];
#pragma unroll
    for (int r = 0; r < 2; ++r) {
        int i = m0 + r * 64 + srow;
        i = (i < cnt) ? i : (cnt - 1);
        ap[r] = ga + (size_t)i * D_FF + scol;
    }
    const ushort_t* w2e = w2t + (size_t)z * D_MODEL * D_FF;
    const ushort_t* bp[2];
#pragma unroll
    for (int r = 0; r < 2; ++r)
        bp[r] = w2e + (size_t)(n0 + r * 64 + srow) * D_FF + scol;

    auto stage = [&](ushort_t* dA, ushort_t* dB, int kk) {
#pragma unroll
        for (int r = 0; r < 2; ++r) {
            gload16(ap[r] + kk, dA + r * 2048 + wave * 512);
            gload16(bp[r] + kk, dB + r * 2048 + wave * 512);
        }
    };
    auto compute = [&](const ushort_t* pA, const ushort_t* pB) {
        const int ko = (lane >> 4) * 8;
        const int fr = lane & 15;
        bf16x8 a[4], b[4];
#pragma unroll
        for (int fm = 0; fm < 4; ++fm)
            a[fm] = *reinterpret_cast<const bf16x8*>(&pA[(wr * 64 + fm * 16 + fr) * 32 + ko]);
#pragma unroll
        for (int fn = 0; fn < 4; ++fn)
            b[fn] = *reinterpret_cast<const bf16x8*>(&pB[(wc * 64 + fn * 16 + fr) * 32 + ko]);
#pragma unroll
        for (int fm = 0; fm < 4; ++fm)
#pragma unroll
            for (int fn = 0; fn < 4; ++fn)
                acc[fm][fn] = __builtin_amdgcn_mfma_f32_16x16x32_bf16(a[fm], b[fn], acc[fm][fn], 0, 0, 0);
    };

    // counted-vmcnt pipeline: 128 K-steps (4 loads/stage)
    stage(sA0, sB0, 0);
#pragma unroll 1
    for (int t = 0; t < 126; t += 2) {
        stage(sA1, sB1, (t + 1) * 32);
        VMCNT4(); BAR();
        compute(sA0, sB0);
        BAR();
        stage(sA0, sB0, (t + 2) * 32);
        VMCNT4(); BAR();
        compute(sA1, sB1);
        BAR();
    }
    stage(sA1, sB1, 127 * 32);
    VMCNT4(); BAR();
    compute(sA0, sB0);
    BAR();
    VMCNT0(); BAR();
    compute(sA1, sB1);

    float* pe = part + (size_t)ge * TOKENS * D_MODEL;
#pragma unroll
    for (int fm = 0; fm < 4; ++fm) {
#pragma unroll
        for (int r = 0; r < 4; ++r) {
            int row = m0 + wr * 64 + fm * 16 + (lane >> 4) * 4 + r;
            if (row < cnt) {
                float w = wts[(size_t)tok[ge * TOKENS + row] * 8 + ge];
#pragma unroll
                for (int fn = 0; fn < 4; ++fn) {
                    int col = n0 + wc * 64 + fn * 16 + (lane & 15);
                    float bb2 = b2[(size_t)ge * D_MODEL + col];
                    pe[(size_t)row * D_MODEL + col] = (acc[fm][fn][r] + bb2) * w;
                }
            }
        }
    }
}

// ---------------------------------------------------------------- final gather-reduce (one block per token)
__global__ __launch_bounds__(256) void reduce_out_kernel(const float* __restrict__ part, // [E][T][1024]
                                                         const int* __restrict__ pos,    // [T][8]
                                                         float* __restrict__ out) {
    const int t = blockIdx.x;
    const int d = threadIdx.x;   // float4 index, 256*4 = 1024
    float4 s = make_float4(0.f, 0.f, 0.f, 0.f);
#pragma unroll
    for (int e = 0; e < 8; ++e) {
        int p = pos[(size_t)t * 8 + e];
        if (p >= 0) {
            float4 v = reinterpret_cast<const float4*>(part + ((size_t)e * TOKENS + p) * D_MODEL)[d];
            s.x += v.x; s.y += v.y; s.z += v.z; s.w += v.w;
        }
    }
    reinterpret_cast<float4*>(out + (size_t)t * D_MODEL)[d] = s;
}

// ---------------------------------------------------------------- launch
extern "C" void kernel_launch(void* const* d_in, const int* in_sizes, int n_in,
                              void* d_out, int out_size, void* d_ws, size_t ws_size,
                              hipStream_t stream) {
    const float* x  = (const float*)d_in[0];
    const float* Wg = (const float*)d_in[1];
    const float* bg = (const float*)d_in[2];
    const float* W1 = (const float*)d_in[3];
    const float* b1 = (const float*)d_in[4];
    const float* W3 = (const float*)d_in[5];
    const float* b3 = (const float*)d_in[6];
    const float* W2 = (const float*)d_in[7];
    const float* b2 = (const float*)d_in[8];
    float* out = (float*)d_out;

    char* wsb = (char*)d_ws;
    ushort_t* xbf  = (ushort_t*)(wsb);                        // 4 MiB
    float*    wts  = (float*)(wsb + (4u << 20));              // 64 KiB
    float*    probs= (float*)(wsb + (4u << 20) + 65536);      // 64 KiB
    float*    ent  = (float*)(wsb + (4u << 20) + 131072);     // 8 KiB
    int*      tok  = (int*)(wsb + (4u << 20) + 139264);       // 64 KiB
    int*      pos  = (int*)(wsb + (4u << 20) + 204800);       // 64 KiB
    int*      cnts = (int*)(wsb + (4u << 20) + 270336);       // 256 B
    float*    part = (float*)(wsb + (8u << 20));              // 64 MiB ([E][T][1024])

    // per-group buffers after part (ends at 72 MiB)
    const size_t BIG0 = (size_t)72 << 20;
    const size_t PER_E = (size_t)40 << 20;   // w1t+w3t+w2t (24 MB) + gbuf (16 MB)
    int GS = 8;
    if (ws_size < BIG0 + 8 * PER_E) GS = 4;
    if (ws_size < BIG0 + 4 * PER_E) GS = 2;
    if (ws_size < BIG0 + 2 * PER_E) GS = 1;

    char* big = wsb + BIG0;
    const size_t W_SZ = (size_t)GS * ((size_t)D_FF * D_MODEL * 2);   // 8 MiB per expert
    ushort_t* w1t  = (ushort_t*)big;
    ushort_t* w3t  = (ushort_t*)(big + W_SZ);
    ushort_t* w2t  = (ushort_t*)(big + 2 * W_SZ);
    ushort_t* gbuf = (ushort_t*)(big + 3 * W_SZ);

    float* out_scalars = out + FINAL_SIZE;        // [2]
    float* out_act     = out + FINAL_SIZE + 2;    // [TOKENS]

    convert_x_kernel<<<TOKENS * D_MODEL / (256 * 4), 256, 0, stream>>>(x, xbf);
    router_kernel<<<TOKENS / 4, 256, 0, stream>>>(x, Wg, bg, wts, probs, ent, out_act);
    build_lists_kernel<<<1, 512, 0, stream>>>(wts, tok, pos, cnts);
    loss_kernel<<<1, 256, 0, stream>>>(wts, probs, ent, out_scalars);

    for (int g0 = 0; g0 < N_EXP; g0 += GS) {
        // W1/W3: K=1024, N=4096 -> grid (64, 16); W2: K=4096, N=1024 -> (16, 64)
        wconv_kernel<<<dim3(D_FF / 64, D_MODEL / 64, GS), 256, 0, stream>>>(
            W1 + (size_t)g0 * D_MODEL * D_FF, w1t, D_MODEL, D_FF);
        wconv_kernel<<<dim3(D_FF / 64, D_MODEL / 64, GS), 256, 0, stream>>>(
            W3 + (size_t)g0 * D_MODEL * D_FF, w3t, D_MODEL, D_FF);
        wconv_kernel<<<dim3(D_MODEL / 64, D_FF / 64, GS), 256, 0, stream>>>(
            W2 + (size_t)g0 * D_FF * D_MODEL, w2t, D_FF, D_MODEL);

        gemm1_kernel<<<dim3(D_FF / 64, TOKENS / 128, GS), 256, 0, stream>>>(
            xbf, w1t, w3t, b1, b3, tok, cnts, gbuf, g0);
        gemm2_kernel<<<dim3(D_MODEL / 128, TOKENS / 128, GS), 256, 0, stream>>>(
            gbuf, w2t, b2, wts, tok, cnts, part, g0);
    }
    reduce_out_kernel<<<TOKENS, 256, 0, stream>>>(part, pos, out);
}

// Round 13
// 493.832 us; speedup vs baseline: 1.3889x; 1.0740x over previous
//
#include <hip/hip_runtime.h>
#include <hip/hip_bf16.h>
#include <math.h>

// Problem constants
#define D_MODEL 1024
#define D_FF    4096
#define N_EXP   8
#define TOKENS  2048          // 2 * 1024
#define THRESH  0.8f
#define EPS_R   1e-6f

#define FINAL_SIZE (TOKENS * D_MODEL)   // 2097152

typedef unsigned short ushort_t;
typedef __attribute__((ext_vector_type(4))) float f32x4;
typedef __attribute__((ext_vector_type(8))) short bf16x8;
typedef __attribute__((ext_vector_type(8))) unsigned short ushort8_t;

__device__ __forceinline__ unsigned short f2bf(float f) {
    unsigned u = __builtin_bit_cast(unsigned, f);
    unsigned r = (u + 0x7FFFu + ((u >> 16) & 1u)) >> 16;
    return (unsigned short)r;
}
__device__ __forceinline__ float bf2f(unsigned short b) {
    unsigned u = ((unsigned)b) << 16;
    return __builtin_bit_cast(float, u);
}

// async global->LDS, 16B per lane; lds base must be wave-uniform (+lane*16 implicit)
template <typename T>
__device__ __forceinline__ void gload16(const T* gsrc, T* ldst) {
    __builtin_amdgcn_global_load_lds((const __attribute__((address_space(1))) unsigned int*)gsrc,
                                     (__attribute__((address_space(3))) unsigned int*)ldst,
                                     16, 0, 0);
}

// counted-vmcnt pipeline primitives: keep next-tile loads in flight across barriers
#define VMCNT4() asm volatile("s_waitcnt vmcnt(4)" ::: "memory")
#define VMCNT0() asm volatile("s_waitcnt vmcnt(0)" ::: "memory")
#define BAR()    do { __builtin_amdgcn_s_barrier(); asm volatile("" ::: "memory"); } while (0)

// ---------------------------------------------------------------- convert x fp32 -> bf16
__global__ __launch_bounds__(256) void convert_x_kernel(const float* __restrict__ x,
                                                        ushort_t* __restrict__ xbf) {
    int i = blockIdx.x * 256 + threadIdx.x;
    const float4 v = reinterpret_cast<const float4*>(x)[i];
    ushort4 o;
    o.x = f2bf(v.x); o.y = f2bf(v.y); o.z = f2bf(v.z); o.w = f2bf(v.w);
    reinterpret_cast<ushort4*>(xbf)[i] = o;
}

// ---------------------------------------------------------------- merged weight transpose+convert
// One dispatch handles W1, W3, W2 (8192 blocks each). Tile 64(k) x 64(n), 256 thr.
// 64-deep k gives each n-row a full 128B cacheline write (no write amplification).
__global__ __launch_bounds__(256) void wconv_all_kernel(const float* __restrict__ W1,
                                                        const float* __restrict__ W3,
                                                        const float* __restrict__ W2,
                                                        ushort_t* __restrict__ w1t,
                                                        ushort_t* __restrict__ w3t,
                                                        ushort_t* __restrict__ w2t) {
    __shared__ float sT[64][65];   // 16.6 KB, +1 pad
    const int idx = blockIdx.x;
    const int sel = idx >> 13;     // 0:W1 1:W3 2:W2
    const int r = idx & 8191;
    int K, N, k0, n0, e;
    const float* src;
    ushort_t* dst;
    if (sel < 2) {
        K = D_MODEL; N = D_FF;
        n0 = (r & 63) * 64;            // 64 n-tiles
        k0 = ((r >> 6) & 15) * 64;     // 16 k-tiles
        e = r >> 10;
        src = (sel == 0 ? W1 : W3) + (size_t)e * K * N;
        dst = (sel == 0 ? w1t : w3t) + (size_t)e * K * N;
    } else {
        K = D_FF; N = D_MODEL;
        n0 = (r & 15) * 64;            // 16 n-tiles
        k0 = ((r >> 4) & 63) * 64;     // 64 k-tiles
        e = r >> 10;
        src = W2 + (size_t)e * K * N;
        dst = w2t + (size_t)e * K * N;
    }
    const int t = threadIdx.x;
    {
        const int k = t >> 2;              // 0..63
        const int c = (t & 3) * 16;        // 0,16,32,48
        const float* s = src + (size_t)(k0 + k) * N + n0 + c;
#pragma unroll
        for (int j = 0; j < 4; ++j) {
            float4 v = *reinterpret_cast<const float4*>(s + 4 * j);
            sT[k][c + 4 * j + 0] = v.x; sT[k][c + 4 * j + 1] = v.y;
            sT[k][c + 4 * j + 2] = v.z; sT[k][c + 4 * j + 3] = v.w;
        }
    }
    __syncthreads();
    {
        const int n = t >> 2;              // 0..63
        const int ks = (t & 3) * 16;       // 0,16,32,48
        ushort_t* d = dst + (size_t)(n0 + n) * K + k0 + ks;
#pragma unroll
        for (int h = 0; h < 2; ++h) {
            ushort8_t o;
#pragma unroll
            for (int j = 0; j < 8; ++j) o[j] = f2bf(sT[ks + h * 8 + j][n]);
            *reinterpret_cast<ushort8_t*>(d + h * 8) = o;
        }
    }
}

// ---------------------------------------------------------------- router (one wave per token)
__global__ __launch_bounds__(256) void router_kernel(const float* __restrict__ x,
                                                     const float* __restrict__ Wg,
                                                     const float* __restrict__ bg,
                                                     float* __restrict__ wts,     // [T][8]
                                                     float* __restrict__ probs,   // [T][8]
                                                     float* __restrict__ ent,     // [T]
                                                     float* __restrict__ act_out) // [T]
{
    int wave = threadIdx.x >> 6;
    int lane = threadIdx.x & 63;
    int t = blockIdx.x * 4 + wave;

    float acc[8];
#pragma unroll
    for (int e = 0; e < 8; ++e) acc[e] = 0.f;

    const float* xrow = x + (size_t)t * D_MODEL;
    for (int d = lane; d < D_MODEL; d += 64) {
        float xv = xrow[d];
        const float4* wg = reinterpret_cast<const float4*>(Wg + (size_t)d * 8);
        float4 a = wg[0], b = wg[1];
        acc[0] += xv * a.x; acc[1] += xv * a.y; acc[2] += xv * a.z; acc[3] += xv * a.w;
        acc[4] += xv * b.x; acc[5] += xv * b.y; acc[6] += xv * b.z; acc[7] += xv * b.w;
    }
#pragma unroll
    for (int e = 0; e < 8; ++e) {
#pragma unroll
        for (int off = 32; off > 0; off >>= 1) acc[e] += __shfl_xor(acc[e], off);
    }

    if (lane == 0) {
        float l[8], p[8];
        float m = -1e30f;
#pragma unroll
        for (int e = 0; e < 8; ++e) { l[e] = acc[e] + bg[e]; m = fmaxf(m, l[e]); }
        float s = 0.f;
#pragma unroll
        for (int e = 0; e < 8; ++e) { p[e] = expf(l[e] - m); s += p[e]; }
        float inv = 1.f / s;
#pragma unroll
        for (int e = 0; e < 8; ++e) p[e] *= inv;

        int idx[8]; float sp[8];
#pragma unroll
        for (int e = 0; e < 8; ++e) { idx[e] = e; sp[e] = p[e]; }
        for (int i = 0; i < 8; ++i) {
            int best = i;
            for (int j = i + 1; j < 8; ++j) if (sp[j] > sp[best]) best = j;
            float tv = sp[i]; sp[i] = sp[best]; sp[best] = tv;
            int ti = idx[i]; idx[i] = idx[best]; idx[best] = ti;
        }
        float cum = 0.f, asum = 0.f, ap[8];
        int cnt = 0;
        for (int i = 0; i < 8; ++i) {
            int active = (i == 0) || (cum < THRESH);
            cum += sp[i];
            ap[i] = active ? sp[i] : 0.f;
            asum += ap[i];
            cnt += active;
        }
        float rinv = 1.f / (asum + EPS_R);
        float w[8];
        for (int i = 0; i < 8; ++i) w[idx[i]] = ap[i] * rinv;

        float* wrow = wts + (size_t)t * 8;
        float* prow = probs + (size_t)t * 8;
        float e_sum = 0.f;
#pragma unroll
        for (int e = 0; e < 8; ++e) {
            wrow[e] = w[e];
            prow[e] = p[e];
            e_sum -= p[e] * logf(p[e] + EPS_R);
        }
        ent[t] = e_sum;
        act_out[t] = (float)cnt;
    }
}

// ---------------------------------------------------------------- per-expert token compaction
__global__ __launch_bounds__(512) void build_lists_kernel(const float* __restrict__ wts,
                                                          int* __restrict__ tok,   // [8][T]
                                                          int* __restrict__ pos,   // [T][8]
                                                          int* __restrict__ cnt) { // [8]
    const int e = threadIdx.x >> 6;
    const int lane = threadIdx.x & 63;
    int base = 0;
    for (int t0 = 0; t0 < TOKENS; t0 += 64) {
        int t = t0 + lane;
        float w = wts[(size_t)t * 8 + e];
        unsigned long long mask = __ballot(w > 0.f);
        int rank = __popcll(mask & ((1ull << lane) - 1ull));
        if (w > 0.f) {
            tok[e * TOKENS + base + rank] = t;
            pos[(size_t)t * 8 + e] = base + rank;
        } else {
            pos[(size_t)t * 8 + e] = -1;
        }
        base += __popcll(mask);
    }
    if (lane == 0) cnt[e] = base;
}

// ---------------------------------------------------------------- loss reduce (single block, shuffle-based, deterministic)
__global__ __launch_bounds__(256) void loss_kernel(const float* __restrict__ wts,
                                                   const float* __restrict__ probs,
                                                   const float* __restrict__ ent,
                                                   float* __restrict__ out_scalars) // [2]
{
    const int tid = threadIdx.x;
    const int lane = tid & 63;
    const int wv = tid >> 6;
    float fsum[8], psum[8], es = 0.f;
#pragma unroll
    for (int e = 0; e < 8; ++e) { fsum[e] = 0.f; psum[e] = 0.f; }
    for (int t = tid; t < TOKENS; t += 256) {
        const float* wrow = wts + (size_t)t * 8;
        const float* prow = probs + (size_t)t * 8;
#pragma unroll
        for (int e = 0; e < 8; ++e) {
            fsum[e] += (wrow[e] > 0.f) ? 1.f : 0.f;
            psum[e] += prow[e];
        }
        es += ent[t];
    }
    // wave-level shuffle reduction (deterministic)
#pragma unroll
    for (int e = 0; e < 8; ++e) {
#pragma unroll
        for (int off = 32; off > 0; off >>= 1) {
            fsum[e] += __shfl_xor(fsum[e], off);
            psum[e] += __shfl_xor(psum[e], off);
        }
    }
#pragma unroll
    for (int off = 32; off > 0; off >>= 1) es += __shfl_xor(es, off);

    __shared__ float red[4][17];
    if (lane == 0) {
#pragma unroll
        for (int e = 0; e < 8; ++e) { red[wv][e] = fsum[e]; red[wv][8 + e] = psum[e]; }
        red[wv][16] = es;
    }
    __syncthreads();
    if (tid == 0) {
        float tot[17];
#pragma unroll
        for (int q = 0; q < 17; ++q) tot[q] = red[0][q] + red[1][q] + red[2][q] + red[3][q];
        const float invT = 1.f / (float)TOKENS;
        float lb = 0.f;
        for (int e = 0; e < 8; ++e) lb += (tot[e] * invT) * (tot[8 + e] * invT);
        out_scalars[0] = 8.f * lb;
        out_scalars[1] = tot[16] * invT;
    }
}

// ---------------------------------------------------------------- GEMM1 (sparse M, counted-vmcnt dbuf, XCD N-chunk swizzle)
// tile 128(M) x 64(N), BK=32, 4 waves (2x2), dual B (W1,W3); LDS 32 KB dbuf
// [r9-proven: 242 us/dispatch, ~715 TF effective — geometry frozen]
__global__ __launch_bounds__(256, 2) void gemm1_kernel(const ushort_t* __restrict__ xbf, // [T][1024]
                                                       const ushort_t* __restrict__ w1t, // [GS][4096][1024]
                                                       const ushort_t* __restrict__ w3t,
                                                       const float* __restrict__ b1,     // [E][4096]
                                                       const float* __restrict__ b3,
                                                       const int* __restrict__ tok,      // [8][T]
                                                       const int* __restrict__ cnts,     // [8]
                                                       ushort_t* __restrict__ g,         // [GS][T][4096] compacted
                                                       int gbase) {
    const int z = blockIdx.z;
    const int ge = gbase + z;
    const int cnt = cnts[ge];

    // XCD swizzle: each XCD owns a contiguous chunk of 8 N-tiles
    const int NX = D_FF / 64;          // 64
    const int CHUNK = NX / 8;          // 8
    const int orig = blockIdx.x + NX * blockIdx.y;
    const int inner = orig >> 3;
    const int nx = (orig & 7) * CHUNK + (inner & (CHUNK - 1));
    const int ny = inner / CHUNK;      // 0..15
    const int m0 = ny * 128;
    const int n0 = nx * 64;
    if (m0 >= cnt) return;

    __shared__ ushort_t sA0[128 * 32], sA1[128 * 32];
    __shared__ ushort_t sB10[64 * 32], sB11[64 * 32];
    __shared__ ushort_t sB30[64 * 32], sB31[64 * 32];

    const int tid = threadIdx.x;
    const int lane = tid & 63;
    const int wave = tid >> 6;
    const int wr = wave >> 1, wc = wave & 1;

    f32x4 acc1[4][2], acc3[4][2];
#pragma unroll
    for (int i = 0; i < 4; ++i)
#pragma unroll
        for (int j = 0; j < 2; ++j) { acc1[i][j] = (f32x4)0.f; acc3[i][j] = (f32x4)0.f; }

    const int srow = tid >> 2;        // 0..63 (row within staging round)
    const int scol = (tid & 3) * 8;   // bf16 col within 32-wide K slice

    // indirect A row base pointers (token gather), clamped for tail tiles
    const ushort_t* abase[2];
#pragma unroll
    for (int r = 0; r < 2; ++r) {
        int i = m0 + srow + r * 64;
        i = (i < cnt) ? i : (cnt - 1);
        abase[r] = xbf + (size_t)tok[ge * TOKENS + i] * D_MODEL + scol;
    }
    const ushort_t* w1p = w1t + (size_t)z * D_FF * D_MODEL + (size_t)(n0 + srow) * D_MODEL + scol;
    const ushort_t* w3p = w3t + (size_t)z * D_FF * D_MODEL + (size_t)(n0 + srow) * D_MODEL + scol;

    auto stage = [&](ushort_t* dA, ushort_t* dB1, ushort_t* dB3, int kk) {
        gload16(abase[0] + kk, dA + wave * 512);
        gload16(abase[1] + kk, dA + 2048 + wave * 512);
        gload16(w1p + kk, dB1 + wave * 512);
        gload16(w3p + kk, dB3 + wave * 512);
    };
    auto compute = [&](const ushort_t* pA, const ushort_t* pB1, const ushort_t* pB3) {
        const int ko = (lane >> 4) * 8;
        const int fr = lane & 15;
        bf16x8 a[4], u1[2], u3[2];
#pragma unroll
        for (int fm = 0; fm < 4; ++fm)
            a[fm] = *reinterpret_cast<const bf16x8*>(&pA[(wr * 64 + fm * 16 + fr) * 32 + ko]);
#pragma unroll
        for (int fn = 0; fn < 2; ++fn) {
            u1[fn] = *reinterpret_cast<const bf16x8*>(&pB1[(wc * 32 + fn * 16 + fr) * 32 + ko]);
            u3[fn] = *reinterpret_cast<const bf16x8*>(&pB3[(wc * 32 + fn * 16 + fr) * 32 + ko]);
        }
#pragma unroll
        for (int fm = 0; fm < 4; ++fm)
#pragma unroll
            for (int fn = 0; fn < 2; ++fn) {
                acc1[fm][fn] = __builtin_amdgcn_mfma_f32_16x16x32_bf16(a[fm], u1[fn], acc1[fm][fn], 0, 0, 0);
                acc3[fm][fn] = __builtin_amdgcn_mfma_f32_16x16x32_bf16(a[fm], u3[fn], acc3[fm][fn], 0, 0, 0);
            }
    };

    // counted-vmcnt pipeline: 32 K-steps, prefetch 1 tile deep (4 loads/stage)
    stage(sA0, sB10, sB30, 0);
#pragma unroll 1
    for (int t = 0; t < 30; t += 2) {
        stage(sA1, sB11, sB31, (t + 1) * 32);
        VMCNT4(); BAR();
        compute(sA0, sB10, sB30);
        BAR();
        stage(sA0, sB10, sB30, (t + 2) * 32);
        VMCNT4(); BAR();
        compute(sA1, sB11, sB31);
        BAR();
    }
    stage(sA1, sB11, sB31, 31 * 32);
    VMCNT4(); BAR();
    compute(sA0, sB10, sB30);
    BAR();
    VMCNT0(); BAR();
    compute(sA1, sB11, sB31);

    // epilogue: SwiGLU -> bf16 g (compacted rows, guarded)
    ushort_t* ge_out = g + (size_t)z * TOKENS * D_FF;
#pragma unroll
    for (int fn = 0; fn < 2; ++fn) {
        int col = n0 + wc * 32 + fn * 16 + (lane & 15);
        float bb1 = b1[(size_t)ge * D_FF + col];
        float bb3 = b3[(size_t)ge * D_FF + col];
#pragma unroll
        for (int fm = 0; fm < 4; ++fm) {
#pragma unroll
            for (int r = 0; r < 4; ++r) {
                int row = m0 + wr * 64 + fm * 16 + (lane >> 4) * 4 + r;
                if (row < cnt) {
                    float h1 = acc1[fm][fn][r] + bb1;
                    float h3 = acc3[fm][fn][r] + bb3;
                    float gv = (h1 / (1.f + expf(-h1))) * h3;
                    ge_out[(size_t)row * D_FF + col] = f2bf(gv);
                }
            }
        }
    }
}

// ---------------------------------------------------------------- GEMM2 (sparse M, counted-vmcnt dbuf) [r9-proven, bf16 partials]
// tile 128(M) x 128(N), BK=32, 4 waves (2x2, wave 64x64); LDS 32 KB dbuf
__global__ __launch_bounds__(256, 2) void gemm2_kernel(const ushort_t* __restrict__ g,   // [GS][T][4096]
                                                       const ushort_t* __restrict__ w2t, // [GS][1024][4096]
                                                       const float* __restrict__ b2,     // [E][1024]
                                                       const float* __restrict__ wts,    // [T][8]
                                                       const int* __restrict__ tok,      // [8][T]
                                                       const int* __restrict__ cnts,     // [8]
                                                       ushort_t* __restrict__ part,      // [E][T][1024] bf16 compacted
                                                       int gbase) {
    const int z = blockIdx.z;
    const int ge = gbase + z;
    const int cnt = cnts[ge];
    const int m0 = blockIdx.y * 128;
    if (m0 >= cnt) return;
    const int n0 = blockIdx.x * 128;

    __shared__ ushort_t sA0[128 * 32], sA1[128 * 32];
    __shared__ ushort_t sB0[128 * 32], sB1[128 * 32];

    const int tid = threadIdx.x;
    const int lane = tid & 63;
    const int wave = tid >> 6;
    const int wr = wave >> 1, wc = wave & 1;

    f32x4 acc[4][4];
#pragma unroll
    for (int i = 0; i < 4; ++i)
#pragma unroll
        for (int j = 0; j < 4; ++j) acc[i][j] = (f32x4)0.f;

    const int srow = tid >> 2;        // 0..63
    const int scol = (tid & 3) * 8;

    const ushort_t* ga = g + (size_t)z * TOKENS * D_FF;
    const ushort_t* ap[2];
#pragma unroll
    for (int r = 0; r < 2; ++r) {
        int i = m0 + r * 64 + srow;
        i = (i < cnt) ? i : (cnt - 1);
        ap[r] = ga + (size_t)i * D_FF + scol;
    }
    const ushort_t* w2e = w2t + (size_t)z * D_MODEL * D_FF;
    const ushort_t* bp[2];
#pragma unroll
    for (int r = 0; r < 2; ++r)
        bp[r] = w2e + (size_t)(n0 + r * 64 + srow) * D_FF + scol;

    auto stage = [&](ushort_t* dA, ushort_t* dB, int kk) {
#pragma unroll
        for (int r = 0; r < 2; ++r) {
            gload16(ap[r] + kk, dA + r * 2048 + wave * 512);
            gload16(bp[r] + kk, dB + r * 2048 + wave * 512);
        }
    };
    auto compute = [&](const ushort_t* pA, const ushort_t* pB) {
        const int ko = (lane >> 4) * 8;
        const int fr = lane & 15;
        bf16x8 a[4], b[4];
#pragma unroll
        for (int fm = 0; fm < 4; ++fm)
            a[fm] = *reinterpret_cast<const bf16x8*>(&pA[(wr * 64 + fm * 16 + fr) * 32 + ko]);
#pragma unroll
        for (int fn = 0; fn < 4; ++fn)
            b[fn] = *reinterpret_cast<const bf16x8*>(&pB[(wc * 64 + fn * 16 + fr) * 32 + ko]);
#pragma unroll
        for (int fm = 0; fm < 4; ++fm)
#pragma unroll
            for (int fn = 0; fn < 4; ++fn)
                acc[fm][fn] = __builtin_amdgcn_mfma_f32_16x16x32_bf16(a[fm], b[fn], acc[fm][fn], 0, 0, 0);
    };

    // counted-vmcnt pipeline: 128 K-steps (4 loads/stage)
    stage(sA0, sB0, 0);
#pragma unroll 1
    for (int t = 0; t < 126; t += 2) {
        stage(sA1, sB1, (t + 1) * 32);
        VMCNT4(); BAR();
        compute(sA0, sB0);
        BAR();
        stage(sA0, sB0, (t + 2) * 32);
        VMCNT4(); BAR();
        compute(sA1, sB1);
        BAR();
    }
    stage(sA1, sB1, 127 * 32);
    VMCNT4(); BAR();
    compute(sA0, sB0);
    BAR();
    VMCNT0(); BAR();
    compute(sA1, sB1);

    ushort_t* pe = part + (size_t)ge * TOKENS * D_MODEL;
#pragma unroll
    for (int fm = 0; fm < 4; ++fm) {
#pragma unroll
        for (int r = 0; r < 4; ++r) {
            int row = m0 + wr * 64 + fm * 16 + (lane >> 4) * 4 + r;
            if (row < cnt) {
                float w = wts[(size_t)tok[ge * TOKENS + row] * 8 + ge];
#pragma unroll
                for (int fn = 0; fn < 4; ++fn) {
                    int col = n0 + wc * 64 + fn * 16 + (lane & 15);
                    float bb2 = b2[(size_t)ge * D_MODEL + col];
                    pe[(size_t)row * D_MODEL + col] = f2bf((acc[fm][fn][r] + bb2) * w);
                }
            }
        }
    }
}

// ---------------------------------------------------------------- final gather-reduce (one block per token, bf16 partials)
__global__ __launch_bounds__(256) void reduce_out_kernel(const ushort_t* __restrict__ part, // [E][T][1024] bf16
                                                         const int* __restrict__ pos,       // [T][8]
                                                         float* __restrict__ out) {
    const int t = blockIdx.x;
    const int d = threadIdx.x;   // covers 4 cols: 256*4 = 1024
    float4 s = make_float4(0.f, 0.f, 0.f, 0.f);
#pragma unroll
    for (int e = 0; e < 8; ++e) {
        int p = pos[(size_t)t * 8 + e];
        if (p >= 0) {
            ushort4 v = reinterpret_cast<const ushort4*>(part + ((size_t)e * TOKENS + p) * D_MODEL)[d];
            s.x += bf2f(v.x); s.y += bf2f(v.y); s.z += bf2f(v.z); s.w += bf2f(v.w);
        }
    }
    reinterpret_cast<float4*>(out + (size_t)t * D_MODEL)[d] = s;
}

// ---------------------------------------------------------------- launch
extern "C" void kernel_launch(void* const* d_in, const int* in_sizes, int n_in,
                              void* d_out, int out_size, void* d_ws, size_t ws_size,
                              hipStream_t stream) {
    const float* x  = (const float*)d_in[0];
    const float* Wg = (const float*)d_in[1];
    const float* bg = (const float*)d_in[2];
    const float* W1 = (const float*)d_in[3];
    const float* b1 = (const float*)d_in[4];
    const float* W3 = (const float*)d_in[5];
    const float* b3 = (const float*)d_in[6];
    const float* W2 = (const float*)d_in[7];
    const float* b2 = (const float*)d_in[8];
    float* out = (float*)d_out;

    char* wsb = (char*)d_ws;
    ushort_t* xbf  = (ushort_t*)(wsb);                        // 4 MiB
    float*    wts  = (float*)(wsb + (4u << 20));              // 64 KiB
    float*    probs= (float*)(wsb + (4u << 20) + 65536);      // 64 KiB
    float*    ent  = (float*)(wsb + (4u << 20) + 131072);     // 8 KiB
    int*      tok  = (int*)(wsb + (4u << 20) + 139264);       // 64 KiB
    int*      pos  = (int*)(wsb + (4u << 20) + 204800);       // 64 KiB
    int*      cnts = (int*)(wsb + (4u << 20) + 270336);       // 256 B
    ushort_t* part = (ushort_t*)(wsb + (8u << 20));           // 32 MiB used ([E][T][1024] bf16)

    // per-group buffers after part region (layout kept from r9: big at 72 MiB)
    const size_t BIG0 = (size_t)72 << 20;
    const size_t PER_E = (size_t)40 << 20;   // w1t+w3t+w2t (24 MB) + gbuf (16 MB)
    int GS = 8;
    if (ws_size < BIG0 + 8 * PER_E) GS = 4;
    if (ws_size < BIG0 + 4 * PER_E) GS = 2;
    if (ws_size < BIG0 + 2 * PER_E) GS = 1;

    char* big = wsb + BIG0;
    const size_t W_SZ = (size_t)GS * ((size_t)D_FF * D_MODEL * 2);   // 8 MiB per expert
    ushort_t* w1t  = (ushort_t*)big;
    ushort_t* w3t  = (ushort_t*)(big + W_SZ);
    ushort_t* w2t  = (ushort_t*)(big + 2 * W_SZ);
    ushort_t* gbuf = (ushort_t*)(big + 3 * W_SZ);

    float* out_scalars = out + FINAL_SIZE;        // [2]
    float* out_act     = out + FINAL_SIZE + 2;    // [TOKENS]

    convert_x_kernel<<<TOKENS * D_MODEL / (256 * 4), 256, 0, stream>>>(x, xbf);
    router_kernel<<<TOKENS / 4, 256, 0, stream>>>(x, Wg, bg, wts, probs, ent, out_act);
    build_lists_kernel<<<1, 512, 0, stream>>>(wts, tok, pos, cnts);
    loss_kernel<<<1, 256, 0, stream>>>(wts, probs, ent, out_scalars);

    for (int g0 = 0; g0 < N_EXP; g0 += GS) {
        if (GS == 8) {
            wconv_all_kernel<<<3 * 8192, 256, 0, stream>>>(W1, W3, W2, w1t, w3t, w2t);
        } else {
            // fallback path for smaller workspaces: per-group merged convert via 3 sub-ranges
            // (reuse the same kernel on offset pointers; grid covers GS experts each)
            wconv_all_kernel<<<3 * 1024 * GS, 256, 0, stream>>>(
                W1 + (size_t)g0 * D_MODEL * D_FF, W3 + (size_t)g0 * D_MODEL * D_FF,
                W2 + (size_t)g0 * D_FF * D_MODEL, w1t, w3t, w2t);
        }

        gemm1_kernel<<<dim3(D_FF / 64, TOKENS / 128, GS), 256, 0, stream>>>(
            xbf, w1t, w3t, b1, b3, tok, cnts, gbuf, g0);
        gemm2_kernel<<<dim3(D_MODEL / 128, TOKENS / 128, GS), 256, 0, stream>>>(
            gbuf, w2t, b2, wts, tok, cnts, part, g0);
    }
    reduce_out_kernel<<<TOKENS, 256, 0, stream>>>(part, pos, out);
}